// Round 6
// baseline (442.274 us; speedup 1.0000x reference)
//
#include <hip/hip_runtime.h>
#include <math.h>

#define NB 16
#define NH 256
#define NW 256
#define TWO_PI 6.28318530717958647692f
#define FSCALE (1.0f/65536.0f)       // norm='forward' 1/(H*W)

// Workspace layout (floats). ws_size observed = 4x out = 1 GiB; we need 100 MB.
//   [0, 2^24)            G1[b][h][ky][i]   cplx   (K1 -> K2)   16.7M floats
//   [2^24, 2^24+2^22)    X_ft[b][kxidx][ky][i]    (K2 -> K3)    4.2M floats
//   [2^24+2^22, +2^23)   out_ft[b][kxidx][ky][o]  (K3 -> K45)   4.2M floats
#define OFF_X  ((size_t)1 << 24)
#define OFF_OF (((size_t)1 << 24) + ((size_t)1 << 22))
#define WS_FLOATS_NEEDED (((size_t)1 << 24) + ((size_t)2 << 22))

// ---------------- K1: forward DFT over w (real -> 32 complex modes) ----------
// One wave per (b,h). lane&31 = channel-pair, lane>>5 = ky-half.
__global__ __launch_bounds__(256) void k1_dft_w(const float* __restrict__ x,
                                                float* __restrict__ WS) {
    int t = threadIdx.x;
    int wave = t >> 6, lane = t & 63;
    int i2 = lane & 31;              // channel pair: channels 2*i2, 2*i2+1
    int kh = lane >> 5;              // ky = kh*16 + kk
    int bh = blockIdx.x * 4 + wave;  // 0..4095
    __shared__ float2 tw[256];
    { float s, c; sincosf(TWO_PI * (float)t * (1.0f/256.0f), &s, &c);
      tw[t] = make_float2(c, s); }
    __syncthreads();

    const float* xr = x + (size_t)bh * (NW*64) + 2*i2;
    float re[16][2], im[16][2];
#pragma unroll
    for (int kk = 0; kk < 16; ++kk) {
        re[kk][0]=re[kk][1]=im[kk][0]=im[kk][1]=0.f;
    }

    for (int j = 1; j < 64; ++j) {
        float2 xa = *(const float2*)(xr + j*64);          // w=j
        float2 xb = *(const float2*)(xr + (256-j)*64);    // w=256-j
        float2 xc = *(const float2*)(xr + (64+j)*64);     // w=64+j
        float2 xd = *(const float2*)(xr + (192-j)*64);    // w=192-j
        float a0x = xa.x + xb.x, a0y = xa.y + xb.y;
        float d0x = xa.x - xb.x, d0y = xa.y - xb.y;
        float a1x = xc.x + xd.x, a1y = xc.y + xd.y;
        float d1x = xc.x - xd.x, d1y = xc.y - xd.y;
#pragma unroll
        for (int kk = 0; kk < 16; ++kk) {
            int p = ((kh*16 + kk) * j) & 255;
            float2 cs = tw[p];
            float C = cs.x, S = cs.y;
            re[kk][0] = fmaf(a0x, C, re[kk][0]);
            re[kk][1] = fmaf(a0y, C, re[kk][1]);
            im[kk][0] = fmaf(-d0x, S, im[kk][0]);
            im[kk][1] = fmaf(-d0y, S, im[kk][1]);
            if ((kk & 3) == 0) {        // cos=C, sin=S
                re[kk][0] = fmaf(a1x, C, re[kk][0]);
                re[kk][1] = fmaf(a1y, C, re[kk][1]);
                im[kk][0] = fmaf(-d1x, S, im[kk][0]);
                im[kk][1] = fmaf(-d1y, S, im[kk][1]);
            } else if ((kk & 3) == 1) { // cos=-S, sin=C
                re[kk][0] = fmaf(-a1x, S, re[kk][0]);
                re[kk][1] = fmaf(-a1y, S, re[kk][1]);
                im[kk][0] = fmaf(-d1x, C, im[kk][0]);
                im[kk][1] = fmaf(-d1y, C, im[kk][1]);
            } else if ((kk & 3) == 2) { // cos=-C, sin=-S
                re[kk][0] = fmaf(-a1x, C, re[kk][0]);
                re[kk][1] = fmaf(-a1y, C, re[kk][1]);
                im[kk][0] = fmaf(d1x, S, im[kk][0]);
                im[kk][1] = fmaf(d1y, S, im[kk][1]);
            } else {                    // cos=S, sin=-C
                re[kk][0] = fmaf(a1x, S, re[kk][0]);
                re[kk][1] = fmaf(a1y, S, re[kk][1]);
                im[kk][0] = fmaf(d1x, C, im[kk][0]);
                im[kk][1] = fmaf(d1y, C, im[kk][1]);
            }
        }
    }
    float2 e0   = *(const float2*)(xr + 0);
    float2 e64  = *(const float2*)(xr + 64*64);
    float2 e128 = *(const float2*)(xr + 128*64);
    float2 e192 = *(const float2*)(xr + 192*64);
    float a64x = e64.x + e192.x, a64y = e64.y + e192.y;
    float d64x = e64.x - e192.x, d64y = e64.y - e192.y;
#pragma unroll
    for (int kk = 0; kk < 16; ++kk) {
        re[kk][0] += e0.x; re[kk][1] += e0.y;
        if (kk & 1) { re[kk][0] -= e128.x; re[kk][1] -= e128.y; }
        else        { re[kk][0] += e128.x; re[kk][1] += e128.y; }
        if ((kk & 3) == 0)      { re[kk][0] += a64x; re[kk][1] += a64y; }
        else if ((kk & 3) == 1) { im[kk][0] -= d64x; im[kk][1] -= d64y; }
        else if ((kk & 3) == 2) { re[kk][0] -= a64x; re[kk][1] -= a64y; }
        else                    { im[kk][0] += d64x; im[kk][1] += d64y; }
    }
    float* R = WS + (size_t)bh * 4096;
#pragma unroll
    for (int kk = 0; kk < 16; ++kk) {
        int ky = kh*16 + kk;
        *(float4*)(R + 2*(ky*64 + 2*i2)) =
            make_float4(re[kk][0]*FSCALE, im[kk][0]*FSCALE,
                        re[kk][1]*FSCALE, im[kk][1]*FSCALE);
    }
}

// ---------------- K2: forward DFT over h (keep 64 kx modes, +/- symmetry) ----
__global__ __launch_bounds__(512) void k2_dft_h(float* __restrict__ WS) {
    int b  = blockIdx.x >> 5;
    int ky = blockIdx.x & 31;
    int t  = threadIdx.x;
    int i  = t & 63;
    int kg = t >> 6;                 // 0..7
    __shared__ float2 tw[256];
    if (t < 256) { float s, c; sincosf(TWO_PI * (float)t * (1.0f/256.0f), &s, &c);
                   tw[t] = make_float2(c, s); }
    __syncthreads();

    float Ar[4]={0,0,0,0}, Ai[4]={0,0,0,0};
    float Br[4]={0,0,0,0}, Bi[4]={0,0,0,0};
    float S0r = 0.f, S0i = 0.f;      // kx=0 accumulator (kg==0 only)
    const float* base = WS + (size_t)b*NH*4096 + 2*(ky*64 + i);

    for (int j = 1; j < 64; ++j) {
        float2 g0 = *(const float2*)(base + (size_t)j*4096);
        float2 g1 = *(const float2*)(base + (size_t)(256-j)*4096);
        float2 g2 = *(const float2*)(base + (size_t)(64+j)*4096);
        float2 g3 = *(const float2*)(base + (size_t)(192-j)*4096);
        float P0r = g0.x + g1.x, P0i = g0.y + g1.y;
        float M0r = g0.x - g1.x, M0i = g0.y - g1.y;
        float P1r = g2.x + g3.x, P1i = g2.y + g3.y;
        float M1r = g2.x - g3.x, M1i = g2.y - g3.y;
#pragma unroll
        for (int q = 0; q < 4; ++q) {
            int m = kg*4 + q;
            if (kg == 0 && q == 0) {
                float PSr = P0r + P1r, PSi = P0i + P1i;
                float MSr = M0r + M1r, MSi = M0i + M1i;
                S0r += PSr; S0i += PSi;
                float2 cs = tw[(224*j) & 255];
                Ar[0]=fmaf(PSr,cs.x,Ar[0]); Ai[0]=fmaf(PSi,cs.x,Ai[0]);
                Br[0]=fmaf(MSr,cs.y,Br[0]); Bi[0]=fmaf(MSi,cs.y,Bi[0]);
            } else {
                float2 cs = tw[(m*j) & 255];
                float C = cs.x, S = cs.y;
                Ar[q]=fmaf(P0r,C,Ar[q]); Ai[q]=fmaf(P0i,C,Ai[q]);
                Br[q]=fmaf(M0r,S,Br[q]); Bi[q]=fmaf(M0i,S,Bi[q]);
                float C2, S2;
                if (q == 0)      { C2 = C;  S2 = S;  }
                else if (q == 1) { C2 = -S; S2 = C;  }
                else if (q == 2) { C2 = -C; S2 = -S; }
                else             { C2 = S;  S2 = -C; }
                Ar[q]=fmaf(P1r,C2,Ar[q]); Ai[q]=fmaf(P1i,C2,Ai[q]);
                Br[q]=fmaf(M1r,S2,Br[q]); Bi[q]=fmaf(M1i,S2,Bi[q]);
            }
        }
    }
    {
        float2 e0   = *(const float2*)(base + (size_t)0);
        float2 e64  = *(const float2*)(base + (size_t)64*4096);
        float2 e128 = *(const float2*)(base + (size_t)128*4096);
        float2 e192 = *(const float2*)(base + (size_t)192*4096);
        float p64r = e64.x + e192.x, p64i = e64.y + e192.y;
        float m64r = e64.x - e192.x, m64i = e64.y - e192.y;
#pragma unroll
        for (int q = 0; q < 4; ++q) {
            if (kg == 0 && q == 0) {
                S0r += e0.x + e64.x + e128.x + e192.x;
                S0i += e0.y + e64.y + e128.y + e192.y;
                Ar[0] += e0.x + e128.x + p64r;
                Ai[0] += e0.y + e128.y + p64i;
            } else {
                Ar[q] += e0.x; Ai[q] += e0.y;
                if ((q & 1) == 0) { Ar[q] += e128.x; Ai[q] += e128.y; }
                else              { Ar[q] -= e128.x; Ai[q] -= e128.y; }
                if (q == 0)      { Ar[q] += p64r; Ai[q] += p64i; }
                else if (q == 1) { Br[q] += m64r; Bi[q] += m64i; }
                else if (q == 2) { Ar[q] -= p64r; Ai[q] -= p64i; }
                else             { Br[q] -= m64r; Bi[q] -= m64i; }
            }
        }
    }
#pragma unroll
    for (int q = 0; q < 4; ++q) {
        int m = kg*4 + q;
        if (kg == 0 && q == 0) {
            float* p0w = WS + OFF_X + (((size_t)b*64 + 0)*32 + ky)*128 + 2*i;
            *(float2*)p0w = make_float2(S0r, S0i);
            float* p32 = WS + OFF_X + (((size_t)b*64 + 32)*32 + ky)*128 + 2*i;
            *(float2*)p32 = make_float2(Ar[0] + Bi[0], Ai[0] - Br[0]);
        } else {
            float* pa = WS + OFF_X + (((size_t)b*64 + m)*32 + ky)*128 + 2*i;
            *(float2*)pa = make_float2(Ar[q] + Bi[q], Ai[q] - Br[q]);
            float* pb = WS + OFF_X + (((size_t)b*64 + (64-m))*32 + ky)*128 + 2*i;
            *(float2*)pb = make_float2(Ar[q] - Bi[q], Ai[q] + Br[q]);
        }
    }
}

// ---------------- K3: channel mixing (complex 64x64 per (kx,ky)) -------------
// block (kx, kyq): stage X for all 16 b in LDS; stream original-layout
// weights per 4-i tile into double-buffered LDS, software-pipelined.
__global__ __launch_bounds__(512) void k3_mix(const float* __restrict__ w1re,
                                              const float* __restrict__ w1im,
                                              const float* __restrict__ w2re,
                                              const float* __restrict__ w2im,
                                              float* __restrict__ WS) {
    int kx  = blockIdx.x >> 2;       // 0..63
    int kyq = blockIdx.x & 3;        // ky = kyq*8 + kyl
    int t   = threadIdx.x;
    __shared__ float2 lx[8192];      // [b][ky8][i] = 64 KB
    __shared__ float  lw[2][2][4][576];  // [buf][re/im][i4][o*9+ky8] = 36 KB
    const float* wre = (kx < 32) ? w1re : w2re;
    const float* wim = (kx < 32) ? w1im : w2im;
    int m = kx & 31;
    for (int n = t; n < 8192; n += 512) {
        int bb = n >> 9, ky8 = (n >> 6) & 7, ii = n & 63;
        lx[n] = *(const float2*)(WS + OFF_X
                 + (((size_t)bb*64 + kx)*32 + kyq*8 + ky8)*128 + 2*ii);
    }
    int sarr = t & 1, so = (t >> 1) & 63, si4 = t >> 7;
    const float* wsrc = sarr ? wim : wre;
    size_t sbase = (size_t)m*32 + kyq*8;
    int kyl = t >> 6;                // 0..7
    int o   = t & 63;
    int kyg = kyq*8 + kyl;
    float ar[16], ai[16];
#pragma unroll
    for (int bb = 0; bb < 16; ++bb) { ar[bb] = 0.f; ai[bb] = 0.f; }

    float4 wa, wb;
    {
        const float* src = wsrc + ((size_t)(si4*64 + so)*1024 + sbase);
        wa = *(const float4*)src; wb = *(const float4*)(src + 4);
        float* dst = &lw[0][sarr][si4][so*9];
        dst[0]=wa.x; dst[1]=wa.y; dst[2]=wa.z; dst[3]=wa.w;
        dst[4]=wb.x; dst[5]=wb.y; dst[6]=wb.z; dst[7]=wb.w;
    }
    __syncthreads();

    for (int k = 0; k < 16; ++k) {
        int i0 = k*4;
        float4 na, nb;
        if (k < 15) {
            const float* src = wsrc + ((size_t)((i0+4+si4)*64 + so)*1024 + sbase);
            na = *(const float4*)src; nb = *(const float4*)(src + 4);
        }
#pragma unroll
        for (int di = 0; di < 4; ++di) {
            float wr = lw[k & 1][0][di][o*9 + kyl];
            float wi = lw[k & 1][1][di][o*9 + kyl];
            int ii = i0 + di;
#pragma unroll
            for (int bb = 0; bb < 16; ++bb) {
                float2 xv = lx[(bb*8 + kyl)*64 + ii];
                ar[bb] = fmaf(xv.x, wr, fmaf(-xv.y, wi, ar[bb]));
                ai[bb] = fmaf(xv.x, wi, fmaf( xv.y, wr, ai[bb]));
            }
        }
        if (k < 15) {
            float* dst = &lw[(k+1) & 1][sarr][si4][so*9];
            dst[0]=na.x; dst[1]=na.y; dst[2]=na.z; dst[3]=na.w;
            dst[4]=nb.x; dst[5]=nb.y; dst[6]=nb.z; dst[7]=nb.w;
        }
        __syncthreads();
    }
#pragma unroll
    for (int bb = 0; bb < 16; ++bb) {
        float* cp = WS + OFF_OF + (((size_t)bb*64 + kx)*32 + kyg)*128 + 2*o;
        *(float2*)cp = make_float2(ar[bb], ai[bb]);
    }
}

// ---------------- K45: fused inverse DFT over h + inverse rfft over w --------
// block = (b, hg 0..63): leads h0=2hg, 2hg+1; entries {L0, M0|128, L1, M1}.
// Phase 1: +/-kx-paired h-iDFT into regs (thread owns 4 (ky,o) cplx pairs).
// Phase 2: 4 tmp rows -> LDS; wave (slot,jq), lane=o; +/-w symmetric iDFT;
// writes final output + bias. No cross-lane ops.
__global__ __launch_bounds__(512) void k45_ih_iw(const float* __restrict__ bias,
                                                 const float* __restrict__ WS,
                                                 float* __restrict__ out) {
    int b  = blockIdx.x >> 6;        // 0..15
    int hg = blockIdx.x & 63;
    int h0 = hg*2;
    int t  = threadIdx.x;
    __shared__ float2 tw[256];
    __shared__ float  ltmp[4*4096];  // 64 KB: 4 h-rows of tmp
    if (t < 256) { float s, c; sincosf(TWO_PI * (float)t * (1.0f/256.0f), &s, &c);
                   tw[t] = make_float2(c, s); }
    __syncthreads();

    // ---- phase 1 ----
    const float* obase = WS + OFF_OF + (size_t)b*64*4096 + t*8;
    float Ar[2][4], Ai_[2][4], Br[2][4], Bi_[2][4];
#pragma unroll
    for (int hh = 0; hh < 2; ++hh)
#pragma unroll
        for (int c = 0; c < 4; ++c) { Ar[hh][c]=Ai_[hh][c]=Br[hh][c]=Bi_[hh][c]=0.f; }
    float A128r[4], A128i[4];
    // singles: kxidx 0 (kx=0), kxidx 32 (kx=224)
    float4 s0a = *(const float4*)(obase);
    float4 s0b = *(const float4*)(obase + 4);
    float4 s2a = *(const float4*)(obase + (size_t)32*4096);
    float4 s2b = *(const float4*)(obase + (size_t)32*4096 + 4);
    float o0r[4] = {s0a.x, s0a.z, s0b.x, s0b.z};
    float o0i[4] = {s0a.y, s0a.w, s0b.y, s0b.w};
    float o2r[4] = {s2a.x, s2a.z, s2b.x, s2b.z};
    float o2i[4] = {s2a.y, s2a.w, s2b.y, s2b.w};
#pragma unroll
    for (int hh = 0; hh < 2; ++hh) {
        int h = h0 + hh;
        float2 cs = tw[(224*h) & 255];
#pragma unroll
        for (int c = 0; c < 4; ++c) {
            Ar[hh][c] += o0r[c];  Ai_[hh][c] += o0i[c];
            Ar[hh][c]  = fmaf(o2r[c], cs.x, Ar[hh][c]);
            Ai_[hh][c] = fmaf(o2i[c], cs.x, Ai_[hh][c]);
            Br[hh][c]  = fmaf(o2r[c], cs.y, Br[hh][c]);
            Bi_[hh][c] = fmaf(o2i[c], cs.y, Bi_[hh][c]);
        }
    }
    if (hg == 0) {
#pragma unroll
        for (int c = 0; c < 4; ++c) { A128r[c] = o0r[c] + o2r[c];
                                      A128i[c] = o0i[c] + o2i[c]; }
    }
    for (int mm = 1; mm < 32; ++mm) {
        const float* pa = obase + (size_t)mm*4096;
        const float* pb = obase + (size_t)(64-mm)*4096;
        float4 a01 = *(const float4*)pa;
        float4 a23 = *(const float4*)(pa + 4);
        float4 b01 = *(const float4*)pb;
        float4 b23 = *(const float4*)(pb + 4);
        float Pr[4]  = {a01.x+b01.x, a01.z+b01.z, a23.x+b23.x, a23.z+b23.z};
        float Pi_[4] = {a01.y+b01.y, a01.w+b01.w, a23.y+b23.y, a23.w+b23.w};
        float Mr[4]  = {a01.x-b01.x, a01.z-b01.z, a23.x-b23.x, a23.z-b23.z};
        float Mi_[4] = {a01.y-b01.y, a01.w-b01.w, a23.y-b23.y, a23.w-b23.w};
#pragma unroll
        for (int hh = 0; hh < 2; ++hh) {
            float2 cs = tw[(mm*(h0+hh)) & 255];
#pragma unroll
            for (int c = 0; c < 4; ++c) {
                Ar[hh][c]  = fmaf(Pr[c],  cs.x, Ar[hh][c]);
                Ai_[hh][c] = fmaf(Pi_[c], cs.x, Ai_[hh][c]);
                Br[hh][c]  = fmaf(Mr[c],  cs.y, Br[hh][c]);
                Bi_[hh][c] = fmaf(Mi_[c], cs.y, Bi_[hh][c]);
            }
        }
        if (hg == 0) {
            float sg = (mm & 1) ? -1.f : 1.f;
#pragma unroll
            for (int c = 0; c < 4; ++c) {
                A128r[c] = fmaf(sg, Pr[c],  A128r[c]);
                A128i[c] = fmaf(sg, Pi_[c], A128i[c]);
            }
        }
    }
    // ---- write 4 tmp rows to LDS ----
#pragma unroll
    for (int e = 0; e < 4; ++e) {
        int hh = e >> 1, em = e & 1;
        float v0, v1, v2, v3, v4, v5, v6, v7;
        if (em == 0) {               // lead
            v0 = Ar[hh][0]-Bi_[hh][0]; v1 = Ai_[hh][0]+Br[hh][0];
            v2 = Ar[hh][1]-Bi_[hh][1]; v3 = Ai_[hh][1]+Br[hh][1];
            v4 = Ar[hh][2]-Bi_[hh][2]; v5 = Ai_[hh][2]+Br[hh][2];
            v6 = Ar[hh][3]-Bi_[hh][3]; v7 = Ai_[hh][3]+Br[hh][3];
        } else if (hg == 0 && hh == 0) {   // h=128
            v0 = A128r[0]; v1 = A128i[0]; v2 = A128r[1]; v3 = A128i[1];
            v4 = A128r[2]; v5 = A128i[2]; v6 = A128r[3]; v7 = A128i[3];
        } else {                     // mirror
            v0 = Ar[hh][0]+Bi_[hh][0]; v1 = Ai_[hh][0]-Br[hh][0];
            v2 = Ar[hh][1]+Bi_[hh][1]; v3 = Ai_[hh][1]-Br[hh][1];
            v4 = Ar[hh][2]+Bi_[hh][2]; v5 = Ai_[hh][2]-Br[hh][2];
            v6 = Ar[hh][3]+Bi_[hh][3]; v7 = Ai_[hh][3]-Br[hh][3];
        }
        float* dst = &ltmp[e*4096 + t*8];
        *(float4*)dst     = make_float4(v0, v1, v2, v3);
        *(float4*)(dst+4) = make_float4(v4, v5, v6, v7);
    }
    __syncthreads();

    // ---- phase 2 ----
    int wv = t >> 6, o = t & 63;
    int slot = wv & 3, jq = wv >> 2;
    int shh = slot >> 1, sm = slot & 1;
    int h = (sm == 0) ? (h0 + shh)
                      : ((hg == 0 && shh == 0) ? 128 : 256 - (h0 + shh));
    float trr[32], tii[32];
    const float2* ls2 = (const float2*)&ltmp[slot*4096];
#pragma unroll
    for (int ky = 0; ky < 32; ++ky) {
        float2 v = ls2[ky*64 + o];
        float sc = (ky == 0) ? 1.f : 2.f;   // Hermitian doubling; bin0 real-only
        trr[ky] = v.x*sc; tii[ky] = v.y*sc;
    }
    float bv = bias[o];
    float* R = out + (size_t)(b*256 + h)*16384 + o;
    for (int jj = 0; jj < 32; ++jj) {
        int j = jq*32 + jj;
        if (j == 0) {                // edges w = 0,64,128,192
            float sA=0.f, sB=0.f, P1=0.f, P2=0.f;
#pragma unroll
            for (int ky = 0; ky < 32; ++ky) {
                sA += trr[ky];
                sB += (ky & 1) ? -trr[ky] : trr[ky];
                if ((ky & 3) == 0) P1 += trr[ky];
                else if ((ky & 3) == 2) P1 -= trr[ky];
                else if ((ky & 3) == 1) P2 += tii[ky];
                else P2 -= tii[ky];
            }
            R[0]      = bv + sA;
            R[64*64]  = bv + P1 - P2;
            R[128*64] = bv + sB;
            R[192*64] = bv + P1 + P2;
        } else {
            float E0=0.f, Od0=0.f, E1=0.f, Od1=0.f;
#pragma unroll
            for (int ky = 0; ky < 32; ++ky) {
                float2 cs = tw[(ky*j) & 255];
                float C = cs.x, S = cs.y;
                E0  = fmaf(trr[ky], C, E0);
                Od0 = fmaf(tii[ky], S, Od0);
                if ((ky & 3) == 0)      { E1 = fmaf(trr[ky], C, E1);
                                          Od1 = fmaf(tii[ky], S, Od1); }
                else if ((ky & 3) == 1) { E1 = fmaf(-trr[ky], S, E1);
                                          Od1 = fmaf(tii[ky], C, Od1); }
                else if ((ky & 3) == 2) { E1 = fmaf(-trr[ky], C, E1);
                                          Od1 = fmaf(-tii[ky], S, Od1); }
                else                    { E1 = fmaf(trr[ky], S, E1);
                                          Od1 = fmaf(-tii[ky], C, Od1); }
            }
            R[j*64]       = bv + E0 - Od0;
            R[(256-j)*64] = bv + E0 + Od0;
            R[(64+j)*64]  = bv + E1 - Od1;
            R[(192-j)*64] = bv + E1 + Od1;
        }
    }
}

extern "C" void kernel_launch(void* const* d_in, const int* in_sizes, int n_in,
                              void* d_out, int out_size, void* d_ws, size_t ws_size,
                              hipStream_t stream) {
    (void)in_sizes; (void)n_in; (void)out_size;
    if (ws_size < WS_FLOATS_NEEDED * sizeof(float)) return;  // ws observed = 1 GiB
    const float* x    = (const float*)d_in[0];
    const float* w1re = (const float*)d_in[1];
    const float* w1im = (const float*)d_in[2];
    const float* w2re = (const float*)d_in[3];
    const float* w2im = (const float*)d_in[4];
    const float* bias = (const float*)d_in[5];
    float* O  = (float*)d_out;
    float* WS = (float*)d_ws;

    k1_dft_w <<<1024, 256, 0, stream>>>(x, WS);
    k2_dft_h <<< 512, 512, 0, stream>>>(WS);
    k3_mix   <<< 256, 512, 0, stream>>>(w1re, w1im, w2re, w2im, WS);
    k45_ih_iw<<<1024, 512, 0, stream>>>(bias, WS, O);
}

// Round 7
// 335.888 us; speedup vs baseline: 1.3167x; 1.3167x over previous
//
#include <hip/hip_runtime.h>
#include <math.h>

#define NB 16
#define NH 256
#define NW 256
#define TWO_PI 6.28318530717958647692f
#define FSCALE (1.0f/65536.0f)       // norm='forward' 1/(H*W)

// Workspace layout (floats). ws_size = 1 GiB; we use 84 MB.
//   [0, 2^24)            G1[b][h][ky][i] cplx (K1 -> K2), then reused as
//                        tmp[b][h][ky][o] cplx (K4 -> K5)
//   [2^24, 2^24+2^22)    X_ft[b][kx][ky][i]  (K2 -> K3)
//   [2^24+2^22, +2^23)   out_ft[b][kx][ky][o] (K3 -> K4)
#define OFF_X  ((size_t)1 << 24)
#define OFF_OF (((size_t)1 << 24) + ((size_t)1 << 22))
#define WS_FLOATS_NEEDED (((size_t)1 << 24) + ((size_t)2 << 22))

// ---------------- K1: forward DFT over w (real -> 32 complex modes) ----------
// One wave per (b,h). lane&31 = channel-pair, lane>>5 = ky-half.
__global__ __launch_bounds__(256) void k1_dft_w(const float* __restrict__ x,
                                                float* __restrict__ WS) {
    int t = threadIdx.x;
    int wave = t >> 6, lane = t & 63;
    int i2 = lane & 31;              // channel pair: channels 2*i2, 2*i2+1
    int kh = lane >> 5;              // ky = kh*16 + kk
    int bh = blockIdx.x * 4 + wave;  // 0..4095
    __shared__ float2 tw[256];
    { float s, c; sincosf(TWO_PI * (float)t * (1.0f/256.0f), &s, &c);
      tw[t] = make_float2(c, s); }
    __syncthreads();

    const float* xr = x + (size_t)bh * (NW*64) + 2*i2;
    float re[16][2], im[16][2];
#pragma unroll
    for (int kk = 0; kk < 16; ++kk) {
        re[kk][0]=re[kk][1]=im[kk][0]=im[kk][1]=0.f;
    }

    for (int j = 1; j < 64; ++j) {
        float2 xa = *(const float2*)(xr + j*64);          // w=j
        float2 xb = *(const float2*)(xr + (256-j)*64);    // w=256-j
        float2 xc = *(const float2*)(xr + (64+j)*64);     // w=64+j
        float2 xd = *(const float2*)(xr + (192-j)*64);    // w=192-j
        float a0x = xa.x + xb.x, a0y = xa.y + xb.y;
        float d0x = xa.x - xb.x, d0y = xa.y - xb.y;
        float a1x = xc.x + xd.x, a1y = xc.y + xd.y;
        float d1x = xc.x - xd.x, d1y = xc.y - xd.y;
#pragma unroll
        for (int kk = 0; kk < 16; ++kk) {
            int p = ((kh*16 + kk) * j) & 255;
            float2 cs = tw[p];
            float C = cs.x, S = cs.y;
            re[kk][0] = fmaf(a0x, C, re[kk][0]);
            re[kk][1] = fmaf(a0y, C, re[kk][1]);
            im[kk][0] = fmaf(-d0x, S, im[kk][0]);
            im[kk][1] = fmaf(-d0y, S, im[kk][1]);
            if ((kk & 3) == 0) {        // cos=C, sin=S
                re[kk][0] = fmaf(a1x, C, re[kk][0]);
                re[kk][1] = fmaf(a1y, C, re[kk][1]);
                im[kk][0] = fmaf(-d1x, S, im[kk][0]);
                im[kk][1] = fmaf(-d1y, S, im[kk][1]);
            } else if ((kk & 3) == 1) { // cos=-S, sin=C
                re[kk][0] = fmaf(-a1x, S, re[kk][0]);
                re[kk][1] = fmaf(-a1y, S, re[kk][1]);
                im[kk][0] = fmaf(-d1x, C, im[kk][0]);
                im[kk][1] = fmaf(-d1y, C, im[kk][1]);
            } else if ((kk & 3) == 2) { // cos=-C, sin=-S
                re[kk][0] = fmaf(-a1x, C, re[kk][0]);
                re[kk][1] = fmaf(-a1y, C, re[kk][1]);
                im[kk][0] = fmaf(d1x, S, im[kk][0]);
                im[kk][1] = fmaf(d1y, S, im[kk][1]);
            } else {                    // cos=S, sin=-C
                re[kk][0] = fmaf(a1x, S, re[kk][0]);
                re[kk][1] = fmaf(a1y, S, re[kk][1]);
                im[kk][0] = fmaf(d1x, C, im[kk][0]);
                im[kk][1] = fmaf(d1y, C, im[kk][1]);
            }
        }
    }
    float2 e0   = *(const float2*)(xr + 0);
    float2 e64  = *(const float2*)(xr + 64*64);
    float2 e128 = *(const float2*)(xr + 128*64);
    float2 e192 = *(const float2*)(xr + 192*64);
    float a64x = e64.x + e192.x, a64y = e64.y + e192.y;
    float d64x = e64.x - e192.x, d64y = e64.y - e192.y;
#pragma unroll
    for (int kk = 0; kk < 16; ++kk) {
        re[kk][0] += e0.x; re[kk][1] += e0.y;
        if (kk & 1) { re[kk][0] -= e128.x; re[kk][1] -= e128.y; }
        else        { re[kk][0] += e128.x; re[kk][1] += e128.y; }
        if ((kk & 3) == 0)      { re[kk][0] += a64x; re[kk][1] += a64y; }
        else if ((kk & 3) == 1) { im[kk][0] -= d64x; im[kk][1] -= d64y; }
        else if ((kk & 3) == 2) { re[kk][0] -= a64x; re[kk][1] -= a64y; }
        else                    { im[kk][0] += d64x; im[kk][1] += d64y; }
    }
    float* R = WS + (size_t)bh * 4096;
#pragma unroll
    for (int kk = 0; kk < 16; ++kk) {
        int ky = kh*16 + kk;
        *(float4*)(R + 2*(ky*64 + 2*i2)) =
            make_float4(re[kk][0]*FSCALE, im[kk][0]*FSCALE,
                        re[kk][1]*FSCALE, im[kk][1]*FSCALE);
    }
}

// ---------------- K2: forward DFT over h, LDS-staged, +/- symmetry ----------
// Two phases: stage rows {0..63, 193..255}, accumulate pair0 (j, 256-j);
// stage rows {64..192}, accumulate pair1 (64+j, 192-j) with rotated twiddle.
__global__ __launch_bounds__(512) void k2_dft_h(float* __restrict__ WS) {
    int b  = blockIdx.x >> 5;
    int ky = blockIdx.x & 31;
    int t  = threadIdx.x;
    int i  = t & 63;
    int kg = t >> 6;                 // 0..7
    __shared__ float2 tw[256];
    __shared__ float  lgf[129*128];  // 66 KB staging, slot-major 128 floats/row
    if (t < 256) { float s, c; sincosf(TWO_PI * (float)t * (1.0f/256.0f), &s, &c);
                   tw[t] = make_float2(c, s); }
    const float* gb = WS + (size_t)b*256*4096 + ky*128;   // + h*4096 (+0..127)

    // stage chunk A: slots 0..63 -> rows 0..63; slots 64..126 -> rows 193..255
    for (int n = t; n < 127*32; n += 512) {
        int slot = n >> 5, q4 = n & 31;
        int row  = (slot < 64) ? slot : slot + 129;
        ((float4*)lgf)[slot*32 + q4] =
            *(const float4*)(gb + (size_t)row*4096 + q4*4);
    }
    __syncthreads();

    float Ar[4]={0,0,0,0}, Ai[4]={0,0,0,0};
    float Br[4]={0,0,0,0}, Bi[4]={0,0,0,0};
    float S0r = 0.f, S0i = 0.f;      // kx=0 accumulator (kg==0 slot 0 only)
    const float2* lg2 = (const float2*)lgf;

    for (int j = 1; j < 64; ++j) {
        float2 g0 = lg2[j*64 + i];           // row j
        float2 g1 = lg2[(127-j)*64 + i];     // row 256-j
        float P0r = g0.x + g1.x, P0i = g0.y + g1.y;
        float M0r = g0.x - g1.x, M0i = g0.y - g1.y;
#pragma unroll
        for (int q = 0; q < 4; ++q) {
            int m = kg*4 + q;
            if (kg == 0 && q == 0) {
                S0r += P0r; S0i += P0i;
                float2 cs = tw[(224*j) & 255];
                Ar[0]=fmaf(P0r,cs.x,Ar[0]); Ai[0]=fmaf(P0i,cs.x,Ai[0]);
                Br[0]=fmaf(M0r,cs.y,Br[0]); Bi[0]=fmaf(M0i,cs.y,Bi[0]);
            } else {
                float2 cs = tw[(m*j) & 255];
                Ar[q]=fmaf(P0r,cs.x,Ar[q]); Ai[q]=fmaf(P0i,cs.x,Ai[q]);
                Br[q]=fmaf(M0r,cs.y,Br[q]); Bi[q]=fmaf(M0i,cs.y,Bi[q]);
            }
        }
    }
    {   // edge row 0 (slot 0): contributes to A of every slot, S0 for special
        float2 e0 = lg2[i];
#pragma unroll
        for (int q = 0; q < 4; ++q) {
            if (kg == 0 && q == 0) { S0r += e0.x; S0i += e0.y; }
            Ar[q] += e0.x; Ai[q] += e0.y;
        }
    }
    __syncthreads();
    // stage chunk B: slots 0..128 -> rows 64..192
    for (int n = t; n < 129*32; n += 512) {
        int slot = n >> 5, q4 = n & 31;
        ((float4*)lgf)[slot*32 + q4] =
            *(const float4*)(gb + (size_t)(slot+64)*4096 + q4*4);
    }
    __syncthreads();

    for (int j = 1; j < 64; ++j) {
        float2 g2 = lg2[j*64 + i];           // row 64+j
        float2 g3 = lg2[(128-j)*64 + i];     // row 192-j
        float P1r = g2.x + g3.x, P1i = g2.y + g3.y;
        float M1r = g2.x - g3.x, M1i = g2.y - g3.y;
#pragma unroll
        for (int q = 0; q < 4; ++q) {
            int m = kg*4 + q;
            if (kg == 0 && q == 0) {
                S0r += P1r; S0i += P1i;
                float2 cs = tw[(224*j) & 255];   // 224*64 % 256 == 0: identity rot
                Ar[0]=fmaf(P1r,cs.x,Ar[0]); Ai[0]=fmaf(P1i,cs.x,Ai[0]);
                Br[0]=fmaf(M1r,cs.y,Br[0]); Bi[0]=fmaf(M1i,cs.y,Bi[0]);
            } else {
                float2 cs = tw[(m*j) & 255];
                float C = cs.x, S = cs.y, C2, S2;
                if (q == 0)      { C2 = C;  S2 = S;  }
                else if (q == 1) { C2 = -S; S2 = C;  }
                else if (q == 2) { C2 = -C; S2 = -S; }
                else             { C2 = S;  S2 = -C; }
                Ar[q]=fmaf(P1r,C2,Ar[q]); Ai[q]=fmaf(P1i,C2,Ai[q]);
                Br[q]=fmaf(M1r,S2,Br[q]); Bi[q]=fmaf(M1i,S2,Bi[q]);
            }
        }
    }
    {   // edges rows 64 (slot 0), 128 (slot 64), 192 (slot 128)
        float2 e64  = lg2[i];
        float2 e128 = lg2[64*64 + i];
        float2 e192 = lg2[128*64 + i];
        float p64r = e64.x + e192.x, p64i = e64.y + e192.y;
        float m64r = e64.x - e192.x, m64i = e64.y - e192.y;
#pragma unroll
        for (int q = 0; q < 4; ++q) {
            if (kg == 0 && q == 0) {
                S0r += e64.x + e128.x + e192.x;
                S0i += e64.y + e128.y + e192.y;
                Ar[0] += e128.x + p64r;
                Ai[0] += e128.y + p64i;
            } else {
                if ((q & 1) == 0) { Ar[q] += e128.x; Ai[q] += e128.y; }
                else              { Ar[q] -= e128.x; Ai[q] -= e128.y; }
                if (q == 0)      { Ar[q] += p64r; Ai[q] += p64i; }
                else if (q == 1) { Br[q] += m64r; Bi[q] += m64i; }
                else if (q == 2) { Ar[q] -= p64r; Ai[q] -= p64i; }
                else             { Br[q] -= m64r; Bi[q] -= m64i; }
            }
        }
    }
#pragma unroll
    for (int q = 0; q < 4; ++q) {
        int m = kg*4 + q;
        if (kg == 0 && q == 0) {
            float* p0w = WS + OFF_X + (((size_t)b*64 + 0)*32 + ky)*128 + 2*i;
            *(float2*)p0w = make_float2(S0r, S0i);
            float* p32 = WS + OFF_X + (((size_t)b*64 + 32)*32 + ky)*128 + 2*i;
            *(float2*)p32 = make_float2(Ar[0] + Bi[0], Ai[0] - Br[0]);
        } else {
            float* pa = WS + OFF_X + (((size_t)b*64 + m)*32 + ky)*128 + 2*i;
            *(float2*)pa = make_float2(Ar[q] + Bi[q], Ai[q] - Br[q]);
            float* pb = WS + OFF_X + (((size_t)b*64 + (64-m))*32 + ky)*128 + 2*i;
            *(float2*)pb = make_float2(Ar[q] - Bi[q], Ai[q] + Br[q]);
        }
    }
}

// ---------------- K3: channel mixing (complex 64x64 per (kx,ky)) -------------
// block decode kyq-major so the 4 sibling blocks of one kx (which share weight
// cache lines) land on the same XCD (64 % 8 == 0) -> L2 absorbs line overlap.
__global__ __launch_bounds__(512) void k3_mix(const float* __restrict__ w1re,
                                              const float* __restrict__ w1im,
                                              const float* __restrict__ w2re,
                                              const float* __restrict__ w2im,
                                              float* __restrict__ WS) {
    int kx  = blockIdx.x & 63;       // 0..63
    int kyq = blockIdx.x >> 6;       // 0..3; ky = kyq*8 + kyl
    int t   = threadIdx.x;
    __shared__ float2 lx[8192];      // [b][ky8][i] = 64 KB
    __shared__ float  lw[2][2][4][576];  // [buf][re/im][i4][o*9+ky8] = 36 KB
    const float* wre = (kx < 32) ? w1re : w2re;
    const float* wim = (kx < 32) ? w1im : w2im;
    int m = kx & 31;
    for (int n = t; n < 8192; n += 512) {
        int bb = n >> 9, ky8 = (n >> 6) & 7, ii = n & 63;
        lx[n] = *(const float2*)(WS + OFF_X
                 + (((size_t)bb*64 + kx)*32 + kyq*8 + ky8)*128 + 2*ii);
    }
    int sarr = t & 1, so = (t >> 1) & 63, si4 = t >> 7;
    const float* wsrc = sarr ? wim : wre;
    size_t sbase = (size_t)m*32 + kyq*8;
    int kyl = t >> 6;                // 0..7
    int o   = t & 63;
    int kyg = kyq*8 + kyl;
    float ar[16], ai[16];
#pragma unroll
    for (int bb = 0; bb < 16; ++bb) { ar[bb] = 0.f; ai[bb] = 0.f; }

    float4 wa, wb;
    {
        const float* src = wsrc + ((size_t)(si4*64 + so)*1024 + sbase);
        wa = *(const float4*)src; wb = *(const float4*)(src + 4);
        float* dst = &lw[0][sarr][si4][so*9];
        dst[0]=wa.x; dst[1]=wa.y; dst[2]=wa.z; dst[3]=wa.w;
        dst[4]=wb.x; dst[5]=wb.y; dst[6]=wb.z; dst[7]=wb.w;
    }
    __syncthreads();

    for (int k = 0; k < 16; ++k) {
        int i0 = k*4;
        float4 na, nb;
        if (k < 15) {
            const float* src = wsrc + ((size_t)((i0+4+si4)*64 + so)*1024 + sbase);
            na = *(const float4*)src; nb = *(const float4*)(src + 4);
        }
#pragma unroll
        for (int di = 0; di < 4; ++di) {
            float wr = lw[k & 1][0][di][o*9 + kyl];
            float wi = lw[k & 1][1][di][o*9 + kyl];
            int ii = i0 + di;
#pragma unroll
            for (int bb = 0; bb < 16; ++bb) {
                float2 xv = lx[(bb*8 + kyl)*64 + ii];
                ar[bb] = fmaf(xv.x, wr, fmaf(-xv.y, wi, ar[bb]));
                ai[bb] = fmaf(xv.x, wi, fmaf( xv.y, wr, ai[bb]));
            }
        }
        if (k < 15) {
            float* dst = &lw[(k+1) & 1][sarr][si4][so*9];
            dst[0]=na.x; dst[1]=na.y; dst[2]=na.z; dst[3]=na.w;
            dst[4]=nb.x; dst[5]=nb.y; dst[6]=nb.z; dst[7]=nb.w;
        }
        __syncthreads();
    }
#pragma unroll
    for (int bb = 0; bb < 16; ++bb) {
        float* cp = WS + OFF_OF + (((size_t)bb*64 + kx)*32 + kyg)*128 + 2*o;
        *(float2*)cp = make_float2(ar[bb], ai[bb]);
    }
}

// ---------------- K4: inverse DFT over h (+/- symmetry) ----------------------
// block (b, hg, half): h-leads h0..h0+7; writes lead+mirror rows of tmp
// (into the retired G1 region); hg==0 also writes h=128.
__global__ __launch_bounds__(512) void k4_idft_h(float* __restrict__ WS) {
    int b    = blockIdx.x >> 5;      // 0..15
    int hg   = (blockIdx.x >> 1) & 15;
    int half = blockIdx.x & 1;
    int t    = threadIdx.x;
    __shared__ float2 tw[256];
    if (t < 256) { float s, c; sincosf(TWO_PI * (float)t * (1.0f/256.0f), &s, &c);
                   tw[t] = make_float2(c, s); }
    __syncthreads();
    int ofs = half*2048 + t*4;       // float offset into 4096-float row
    int h0  = hg*8;
    float Are[8][2], Aim[8][2], Bre[8][2], Bim[8][2];
#pragma unroll
    for (int hh = 0; hh < 8; ++hh) {
        Are[hh][0]=Are[hh][1]=Aim[hh][0]=Aim[hh][1]=0.f;
        Bre[hh][0]=Bre[hh][1]=Bim[hh][0]=Bim[hh][1]=0.f;
    }
    const float* obase = WS + OFF_OF + (size_t)b*64*4096 + ofs;
    float4 of0  = *(const float4*)(obase);                 // kxidx 0  (kx=0)
    float4 of32 = *(const float4*)(obase + (size_t)32*4096); // kxidx 32 (kx=224)
    float A128r0 = of0.x + of32.x, A128i0 = of0.y + of32.y;
    float A128r1 = of0.z + of32.z, A128i1 = of0.w + of32.w;
#pragma unroll
    for (int hh = 0; hh < 8; ++hh) {
        int h = h0 + hh;
        Are[hh][0] += of0.x; Aim[hh][0] += of0.y;
        Are[hh][1] += of0.z; Aim[hh][1] += of0.w;
        float2 cs = tw[(224*h) & 255];
        Are[hh][0]=fmaf(of32.x,cs.x,Are[hh][0]); Aim[hh][0]=fmaf(of32.y,cs.x,Aim[hh][0]);
        Are[hh][1]=fmaf(of32.z,cs.x,Are[hh][1]); Aim[hh][1]=fmaf(of32.w,cs.x,Aim[hh][1]);
        Bre[hh][0]=fmaf(of32.x,cs.y,Bre[hh][0]); Bim[hh][0]=fmaf(of32.y,cs.y,Bim[hh][0]);
        Bre[hh][1]=fmaf(of32.z,cs.y,Bre[hh][1]); Bim[hh][1]=fmaf(of32.w,cs.y,Bim[hh][1]);
    }
    for (int mm = 1; mm < 32; ++mm) {
        float4 oa = *(const float4*)(obase + (size_t)mm*4096);
        float4 ob = *(const float4*)(obase + (size_t)(64-mm)*4096);
        float Pr0 = oa.x + ob.x, Pi0 = oa.y + ob.y;
        float Pr1 = oa.z + ob.z, Pi1 = oa.w + ob.w;
        float Mr0 = oa.x - ob.x, Mi0 = oa.y - ob.y;
        float Mr1 = oa.z - ob.z, Mi1 = oa.w - ob.w;
#pragma unroll
        for (int hh = 0; hh < 8; ++hh) {
            float2 cs = tw[(mm*(h0+hh)) & 255];
            float C = cs.x, S = cs.y;
            Are[hh][0]=fmaf(Pr0,C,Are[hh][0]); Aim[hh][0]=fmaf(Pi0,C,Aim[hh][0]);
            Are[hh][1]=fmaf(Pr1,C,Are[hh][1]); Aim[hh][1]=fmaf(Pi1,C,Aim[hh][1]);
            Bre[hh][0]=fmaf(Mr0,S,Bre[hh][0]); Bim[hh][0]=fmaf(Mi0,S,Bim[hh][0]);
            Bre[hh][1]=fmaf(Mr1,S,Bre[hh][1]); Bim[hh][1]=fmaf(Mi1,S,Bim[hh][1]);
        }
        if (hg == 0) {               // h=128: c = (-1)^m, s = 0
            float sg = (mm & 1) ? -1.f : 1.f;
            A128r0 = fmaf(sg, Pr0, A128r0); A128i0 = fmaf(sg, Pi0, A128i0);
            A128r1 = fmaf(sg, Pr1, A128r1); A128i1 = fmaf(sg, Pi1, A128i1);
        }
    }
#pragma unroll
    for (int hh = 0; hh < 8; ++hh) {
        int h = h0 + hh;
        float* dp = WS + (size_t)(b*256 + h)*4096 + ofs;
        *(float4*)dp = make_float4(Are[hh][0]-Bim[hh][0], Aim[hh][0]+Bre[hh][0],
                                   Are[hh][1]-Bim[hh][1], Aim[hh][1]+Bre[hh][1]);
        if (h > 0) {
            float* dq = WS + (size_t)(b*256 + 256 - h)*4096 + ofs;
            *(float4*)dq = make_float4(Are[hh][0]+Bim[hh][0], Aim[hh][0]-Bre[hh][0],
                                       Are[hh][1]+Bim[hh][1], Aim[hh][1]-Bre[hh][1]);
        }
    }
    if (hg == 0) {
        float* dp = WS + (size_t)(b*256 + 128)*4096 + ofs;
        *(float4*)dp = make_float4(A128r0, A128i0, A128r1, A128i1);
    }
}

// ---------------- K5: inverse rfft over w + bias, no shuffles ----------------
// block per (b,h), 256 thr: stage tmp row (16 KB) in LDS; lane = channel,
// full 32-ky loop in registers; wave w owns j = w*16+1 .. w*16+16 (wave 3:
// 15 j's + the four edge columns).
__global__ __launch_bounds__(256) void k5_idft_w(const float* __restrict__ bias,
                                                 const float* __restrict__ WS,
                                                 float* __restrict__ out) {
    int bh = blockIdx.x;             // 0..4095
    int t  = threadIdx.x;
    __shared__ float2 tw[256];
    __shared__ float  lt[4096];
    { float s, c; sincosf(TWO_PI * (float)t * (1.0f/256.0f), &s, &c);
      tw[t] = make_float2(c, s); }
    const float4* T4 = (const float4*)(WS + (size_t)bh*4096);
#pragma unroll
    for (int q = 0; q < 4; ++q)
        ((float4*)lt)[t + 256*q] = T4[t + 256*q];
    __syncthreads();
    int w = t >> 6, o = t & 63;
    float trr[32], tii[32];
    const float2* l2 = (const float2*)lt;
#pragma unroll
    for (int ky = 0; ky < 32; ++ky) {
        float2 p = l2[ky*64 + o];
        float sc = (ky == 0) ? 1.f : 2.f;   // Hermitian doubling; bin0 real-only
        trr[ky] = p.x*sc; tii[ky] = p.y*sc;
    }
    float bv = bias[o];
    float* R = out + (size_t)bh*16384 + o;
    int j0 = w*16;
    for (int jj = 1; jj <= 16; ++jj) {
        int j = j0 + jj;
        if (j < 64) {
            float E0=0.f, Od0=0.f, E1=0.f, Od1=0.f;
#pragma unroll
            for (int ky = 0; ky < 32; ++ky) {
                float2 cs = tw[(ky*j) & 255];
                float C = cs.x, S = cs.y;
                E0  = fmaf(trr[ky], C, E0);
                Od0 = fmaf(tii[ky], S, Od0);
                if ((ky & 3) == 0)      { E1 = fmaf(trr[ky], C, E1);
                                          Od1 = fmaf(tii[ky], S, Od1); }
                else if ((ky & 3) == 1) { E1 = fmaf(-trr[ky], S, E1);
                                          Od1 = fmaf(tii[ky], C, Od1); }
                else if ((ky & 3) == 2) { E1 = fmaf(-trr[ky], C, E1);
                                          Od1 = fmaf(-tii[ky], S, Od1); }
                else                    { E1 = fmaf(trr[ky], S, E1);
                                          Od1 = fmaf(-tii[ky], C, Od1); }
            }
            R[j*64]       = bv + E0 - Od0;
            R[(256-j)*64] = bv + E0 + Od0;
            R[(64+j)*64]  = bv + E1 - Od1;
            R[(192-j)*64] = bv + E1 + Od1;
        } else {                     // wave 3, jj==16: edge columns 0,64,128,192
            float sA=0.f, sB=0.f, P1=0.f, P2=0.f;
#pragma unroll
            for (int ky = 0; ky < 32; ++ky) {
                sA += trr[ky];
                sB += (ky & 1) ? -trr[ky] : trr[ky];
                if ((ky & 3) == 0) P1 += trr[ky];
                else if ((ky & 3) == 2) P1 -= trr[ky];
                else if ((ky & 3) == 1) P2 += tii[ky];
                else P2 -= tii[ky];
            }
            R[0]      = bv + sA;
            R[64*64]  = bv + P1 - P2;
            R[128*64] = bv + sB;
            R[192*64] = bv + P1 + P2;
        }
    }
}

extern "C" void kernel_launch(void* const* d_in, const int* in_sizes, int n_in,
                              void* d_out, int out_size, void* d_ws, size_t ws_size,
                              hipStream_t stream) {
    (void)in_sizes; (void)n_in; (void)out_size;
    if (ws_size < WS_FLOATS_NEEDED * sizeof(float)) return;  // ws observed = 1 GiB
    const float* x    = (const float*)d_in[0];
    const float* w1re = (const float*)d_in[1];
    const float* w1im = (const float*)d_in[2];
    const float* w2re = (const float*)d_in[3];
    const float* w2im = (const float*)d_in[4];
    const float* bias = (const float*)d_in[5];
    float* O  = (float*)d_out;
    float* WS = (float*)d_ws;

    k1_dft_w <<<1024, 256, 0, stream>>>(x, WS);
    k2_dft_h <<< 512, 512, 0, stream>>>(WS);
    k3_mix   <<< 256, 512, 0, stream>>>(w1re, w1im, w2re, w2im, WS);
    k4_idft_h<<< 512, 512, 0, stream>>>(WS);
    k5_idft_w<<<4096, 256, 0, stream>>>(bias, WS, O);
}

// Round 8
// 309.852 us; speedup vs baseline: 1.4274x; 1.0840x over previous
//
#include <hip/hip_runtime.h>
#include <math.h>

#define NB 16
#define NH 256
#define NW 256
#define TWO_PI 6.28318530717958647692f
#define FSCALE (1.0f/65536.0f)       // norm='forward' 1/(H*W)

// Workspace layout (floats). ws_size = 1 GiB; we use 84 MB.
//   [0, 2^24)            G1[b][h][comp][ky][i] planes (K1 -> K2): re at
//                        bh*4096 + ky*64 + i, im at +2048. Then reused as
//                        tmp[b][h][ky][o] interleaved cplx (K4 -> K5).
//   [2^24, 2^24+2^22)    X_ft[b][kx][ky][i]  (K2 -> K3)
//   [2^24+2^22, +2^23)   out_ft[b][kx][ky][o] (K3 -> K4)
#define OFF_X  ((size_t)1 << 24)
#define OFF_OF (((size_t)1 << 24) + ((size_t)1 << 22))
#define WS_FLOATS_NEEDED (((size_t)1 << 24) + ((size_t)2 << 22))

typedef __attribute__((ext_vector_type(8))) short short8;
typedef __attribute__((ext_vector_type(4))) float f32x4;

__device__ __forceinline__ unsigned short f2bf(float f) {
    unsigned int u = __float_as_uint(f);
    unsigned int r = (u + 0x7FFFu + ((u >> 16) & 1u)) >> 16;
    return (unsigned short)r;
}

// ---------------- K1: forward DFT over w via bf16 MFMA ----------------------
// Per (b,h): G1[64 m, 64 i] = T[64 m, 256 w] x[256 w, 64 i], m rows 0..31 =
// FSCALE*cos(ky w th), rows 32..63 = -FSCALE*sin(ky w th). Block = 4 waves,
// 4 (b,h) sequentially; T built once; x staged transposed bf16.
#define XPITCH 264   // ushorts per LDS row (256 + 8 pad -> <=2-way conflicts)
__global__ __launch_bounds__(256) void k1_dft_w(const float* __restrict__ x,
                                                float* __restrict__ WS) {
    __shared__ unsigned short Al[64 * XPITCH];   // T[m][w] bf16, 33 KB
    __shared__ unsigned short Xl[64 * XPITCH];   // x^T[i][w] bf16, 33 KB
    int t = threadIdx.x;
    {   // build T: thread t covers m = t>>2, w = (t&3)*64 .. +63
        int m  = t >> 2;
        int w0 = (t & 3) * 64;
        int ky = m & 31;
        for (int dw = 0; dw < 64; ++dw) {
            int w = w0 + dw;
            float ang = TWO_PI * (float)((ky * w) & 255) * (1.0f/256.0f);
            float s, c; sincosf(ang, &s, &c);
            float v = (m < 32) ? c : -s;
            Al[m * XPITCH + w] = f2bf(v * FSCALE);
        }
    }
    int wave = t >> 6, lane = t & 63;
    int col = lane & 15, kq = lane >> 4;
    for (int u = 0; u < 4; ++u) {
        int bh = blockIdx.x * 4 + u;
        __syncthreads();             // T ready / previous compute done
        {   // stage x^T: thread t owns w-row t; stride-2B LDS writes (no conflict)
            const float* xs = x + (size_t)bh * 16384 + t * 64;
            for (int i4 = 0; i4 < 16; ++i4) {
                float4 v = *(const float4*)(xs + i4*4);
                Xl[(i4*4+0)*XPITCH + t] = f2bf(v.x);
                Xl[(i4*4+1)*XPITCH + t] = f2bf(v.y);
                Xl[(i4*4+2)*XPITCH + t] = f2bf(v.z);
                Xl[(i4*4+3)*XPITCH + t] = f2bf(v.w);
            }
        }
        __syncthreads();
        // wave = M-stripe (rows wave*16 .. +15)
        f32x4 acc[4];
#pragma unroll
        for (int n = 0; n < 4; ++n) acc[n] = (f32x4){0.f, 0.f, 0.f, 0.f};
#pragma unroll
        for (int kk = 0; kk < 8; ++kk) {
            int k = kk*32 + kq*8;
            short8 af = *(const short8*)&Al[(wave*16 + col) * XPITCH + k];
#pragma unroll
            for (int n = 0; n < 4; ++n) {
                short8 bf = *(const short8*)&Xl[(n*16 + col) * XPITCH + k];
                acc[n] = __builtin_amdgcn_mfma_f32_16x16x32_bf16(af, bf, acc[n], 0, 0, 0);
            }
        }
        // store D: row m = wave*16 + kq*4 + q, col i = n*16 + col
        int comp = wave >> 1;        // 0 = re, 1 = im
        int kyb  = (wave & 1) * 16;
        float* gp = WS + (size_t)bh * 4096 + comp * 2048;
#pragma unroll
        for (int n = 0; n < 4; ++n)
#pragma unroll
            for (int q = 0; q < 4; ++q) {
                int ky = kyb + kq*4 + q;
                gp[ky*64 + n*16 + col] = acc[n][q];
            }
    }
}

// ---------------- K2: forward DFT over h, LDS-staged, +/- symmetry ----------
// Reads G1 planes (re at +0, im at +2048 within each 4096-float bh row).
// Two phases: stage rows {0..63, 193..255}, accumulate pair0 (j, 256-j);
// stage rows {64..192}, accumulate pair1 (64+j, 192-j) with rotated twiddle.
__global__ __launch_bounds__(512) void k2_dft_h(float* __restrict__ WS) {
    int b  = blockIdx.x >> 5;
    int ky = blockIdx.x & 31;
    int t  = threadIdx.x;
    int i  = t & 63;
    int kg = t >> 6;                 // 0..7
    __shared__ float2 tw[256];
    __shared__ float  lgf[129*128];  // 66 KB; slot = [re 64 | im 64]
    if (t < 256) { float s, c; sincosf(TWO_PI * (float)t * (1.0f/256.0f), &s, &c);
                   tw[t] = make_float2(c, s); }
    const float* gb = WS + (size_t)b*256*4096 + ky*64;    // + h*4096 (+comp*2048)

    // stage chunk A: slots 0..63 -> rows 0..63; slots 64..126 -> rows 193..255
    for (int n = t; n < 127*32; n += 512) {
        int slot = n >> 5, q = n & 31;
        int comp = q >> 4, qq = q & 15;
        int row  = (slot < 64) ? slot : slot + 129;
        ((float4*)lgf)[slot*32 + q] =
            *(const float4*)(gb + (size_t)row*4096 + comp*2048 + qq*4);
    }
    __syncthreads();

    float Ar[4]={0,0,0,0}, Ai[4]={0,0,0,0};
    float Br[4]={0,0,0,0}, Bi[4]={0,0,0,0};
    float S0r = 0.f, S0i = 0.f;      // kx=0 accumulator (kg==0 slot 0 only)

    for (int j = 1; j < 64; ++j) {
        float g0r = lgf[j*128 + i],        g0i = lgf[j*128 + 64 + i];
        float g1r = lgf[(127-j)*128 + i],  g1i = lgf[(127-j)*128 + 64 + i];
        float P0r = g0r + g1r, P0i = g0i + g1i;
        float M0r = g0r - g1r, M0i = g0i - g1i;
#pragma unroll
        for (int q = 0; q < 4; ++q) {
            int m = kg*4 + q;
            if (kg == 0 && q == 0) {
                S0r += P0r; S0i += P0i;
                float2 cs = tw[(224*j) & 255];
                Ar[0]=fmaf(P0r,cs.x,Ar[0]); Ai[0]=fmaf(P0i,cs.x,Ai[0]);
                Br[0]=fmaf(M0r,cs.y,Br[0]); Bi[0]=fmaf(M0i,cs.y,Bi[0]);
            } else {
                float2 cs = tw[(m*j) & 255];
                Ar[q]=fmaf(P0r,cs.x,Ar[q]); Ai[q]=fmaf(P0i,cs.x,Ai[q]);
                Br[q]=fmaf(M0r,cs.y,Br[q]); Bi[q]=fmaf(M0i,cs.y,Bi[q]);
            }
        }
    }
    {   // edge row 0 (slot 0)
        float e0r = lgf[i], e0i = lgf[64 + i];
#pragma unroll
        for (int q = 0; q < 4; ++q) {
            if (kg == 0 && q == 0) { S0r += e0r; S0i += e0i; }
            Ar[q] += e0r; Ai[q] += e0i;
        }
    }
    __syncthreads();
    // stage chunk B: slots 0..128 -> rows 64..192
    for (int n = t; n < 129*32; n += 512) {
        int slot = n >> 5, q = n & 31;
        int comp = q >> 4, qq = q & 15;
        ((float4*)lgf)[slot*32 + q] =
            *(const float4*)(gb + (size_t)(slot+64)*4096 + comp*2048 + qq*4);
    }
    __syncthreads();

    for (int j = 1; j < 64; ++j) {
        float g2r = lgf[j*128 + i],        g2i = lgf[j*128 + 64 + i];
        float g3r = lgf[(128-j)*128 + i],  g3i = lgf[(128-j)*128 + 64 + i];
        float P1r = g2r + g3r, P1i = g2i + g3i;
        float M1r = g2r - g3r, M1i = g2i - g3i;
#pragma unroll
        for (int q = 0; q < 4; ++q) {
            int m = kg*4 + q;
            if (kg == 0 && q == 0) {
                S0r += P1r; S0i += P1i;
                float2 cs = tw[(224*j) & 255];   // 224*64 % 256 == 0: identity rot
                Ar[0]=fmaf(P1r,cs.x,Ar[0]); Ai[0]=fmaf(P1i,cs.x,Ai[0]);
                Br[0]=fmaf(M1r,cs.y,Br[0]); Bi[0]=fmaf(M1i,cs.y,Bi[0]);
            } else {
                float2 cs = tw[(m*j) & 255];
                float C = cs.x, S = cs.y, C2, S2;
                if (q == 0)      { C2 = C;  S2 = S;  }
                else if (q == 1) { C2 = -S; S2 = C;  }
                else if (q == 2) { C2 = -C; S2 = -S; }
                else             { C2 = S;  S2 = -C; }
                Ar[q]=fmaf(P1r,C2,Ar[q]); Ai[q]=fmaf(P1i,C2,Ai[q]);
                Br[q]=fmaf(M1r,S2,Br[q]); Bi[q]=fmaf(M1i,S2,Bi[q]);
            }
        }
    }
    {   // edges rows 64 (slot 0), 128 (slot 64), 192 (slot 128)
        float e64r  = lgf[i],          e64i  = lgf[64 + i];
        float e128r = lgf[64*128 + i], e128i = lgf[64*128 + 64 + i];
        float e192r = lgf[128*128 + i],e192i = lgf[128*128 + 64 + i];
        float p64r = e64r + e192r, p64i = e64i + e192i;
        float m64r = e64r - e192r, m64i = e64i - e192i;
#pragma unroll
        for (int q = 0; q < 4; ++q) {
            if (kg == 0 && q == 0) {
                S0r += e64r + e128r + e192r;
                S0i += e64i + e128i + e192i;
                Ar[0] += e128r + p64r;
                Ai[0] += e128i + p64i;
            } else {
                if ((q & 1) == 0) { Ar[q] += e128r; Ai[q] += e128i; }
                else              { Ar[q] -= e128r; Ai[q] -= e128i; }
                if (q == 0)      { Ar[q] += p64r; Ai[q] += p64i; }
                else if (q == 1) { Br[q] += m64r; Bi[q] += m64i; }
                else if (q == 2) { Ar[q] -= p64r; Ai[q] -= p64i; }
                else             { Br[q] -= m64r; Bi[q] -= m64i; }
            }
        }
    }
#pragma unroll
    for (int q = 0; q < 4; ++q) {
        int m = kg*4 + q;
        if (kg == 0 && q == 0) {
            float* p0w = WS + OFF_X + (((size_t)b*64 + 0)*32 + ky)*128 + 2*i;
            *(float2*)p0w = make_float2(S0r, S0i);
            float* p32 = WS + OFF_X + (((size_t)b*64 + 32)*32 + ky)*128 + 2*i;
            *(float2*)p32 = make_float2(Ar[0] + Bi[0], Ai[0] - Br[0]);
        } else {
            float* pa = WS + OFF_X + (((size_t)b*64 + m)*32 + ky)*128 + 2*i;
            *(float2*)pa = make_float2(Ar[q] + Bi[q], Ai[q] - Br[q]);
            float* pb = WS + OFF_X + (((size_t)b*64 + (64-m))*32 + ky)*128 + 2*i;
            *(float2*)pb = make_float2(Ar[q] - Bi[q], Ai[q] + Br[q]);
        }
    }
}

// ---------------- K3: channel mixing (complex 64x64 per (kx,ky)) -------------
// block decode kyq-major so the 4 sibling blocks of one kx (which share weight
// cache lines) land on the same XCD (64 % 8 == 0) -> L2 absorbs line overlap.
__global__ __launch_bounds__(512) void k3_mix(const float* __restrict__ w1re,
                                              const float* __restrict__ w1im,
                                              const float* __restrict__ w2re,
                                              const float* __restrict__ w2im,
                                              float* __restrict__ WS) {
    int kx  = blockIdx.x & 63;       // 0..63
    int kyq = blockIdx.x >> 6;       // 0..3; ky = kyq*8 + kyl
    int t   = threadIdx.x;
    __shared__ float2 lx[8192];      // [b][ky8][i] = 64 KB
    __shared__ float  lw[2][2][4][576];  // [buf][re/im][i4][o*9+ky8] = 36 KB
    const float* wre = (kx < 32) ? w1re : w2re;
    const float* wim = (kx < 32) ? w1im : w2im;
    int m = kx & 31;
    for (int n = t; n < 8192; n += 512) {
        int bb = n >> 9, ky8 = (n >> 6) & 7, ii = n & 63;
        lx[n] = *(const float2*)(WS + OFF_X
                 + (((size_t)bb*64 + kx)*32 + kyq*8 + ky8)*128 + 2*ii);
    }
    int sarr = t & 1, so = (t >> 1) & 63, si4 = t >> 7;
    const float* wsrc = sarr ? wim : wre;
    size_t sbase = (size_t)m*32 + kyq*8;
    int kyl = t >> 6;                // 0..7
    int o   = t & 63;
    int kyg = kyq*8 + kyl;
    float ar[16], ai[16];
#pragma unroll
    for (int bb = 0; bb < 16; ++bb) { ar[bb] = 0.f; ai[bb] = 0.f; }

    float4 wa, wb;
    {
        const float* src = wsrc + ((size_t)(si4*64 + so)*1024 + sbase);
        wa = *(const float4*)src; wb = *(const float4*)(src + 4);
        float* dst = &lw[0][sarr][si4][so*9];
        dst[0]=wa.x; dst[1]=wa.y; dst[2]=wa.z; dst[3]=wa.w;
        dst[4]=wb.x; dst[5]=wb.y; dst[6]=wb.z; dst[7]=wb.w;
    }
    __syncthreads();

    for (int k = 0; k < 16; ++k) {
        int i0 = k*4;
        float4 na, nb;
        if (k < 15) {
            const float* src = wsrc + ((size_t)((i0+4+si4)*64 + so)*1024 + sbase);
            na = *(const float4*)src; nb = *(const float4*)(src + 4);
        }
#pragma unroll
        for (int di = 0; di < 4; ++di) {
            float wr = lw[k & 1][0][di][o*9 + kyl];
            float wi = lw[k & 1][1][di][o*9 + kyl];
            int ii = i0 + di;
#pragma unroll
            for (int bb = 0; bb < 16; ++bb) {
                float2 xv = lx[(bb*8 + kyl)*64 + ii];
                ar[bb] = fmaf(xv.x, wr, fmaf(-xv.y, wi, ar[bb]));
                ai[bb] = fmaf(xv.x, wi, fmaf( xv.y, wr, ai[bb]));
            }
        }
        if (k < 15) {
            float* dst = &lw[(k+1) & 1][sarr][si4][so*9];
            dst[0]=na.x; dst[1]=na.y; dst[2]=na.z; dst[3]=na.w;
            dst[4]=nb.x; dst[5]=nb.y; dst[6]=nb.z; dst[7]=nb.w;
        }
        __syncthreads();
    }
#pragma unroll
    for (int bb = 0; bb < 16; ++bb) {
        float* cp = WS + OFF_OF + (((size_t)bb*64 + kx)*32 + kyg)*128 + 2*o;
        *(float2*)cp = make_float2(ar[bb], ai[bb]);
    }
}

// ---------------- K4: inverse DFT over h (+/- symmetry) ----------------------
// block (b, hg, half): h-leads h0..h0+7; writes lead+mirror rows of tmp
// (into the retired G1 region); hg==0 also writes h=128.
__global__ __launch_bounds__(512) void k4_idft_h(float* __restrict__ WS) {
    int b    = blockIdx.x >> 5;      // 0..15
    int hg   = (blockIdx.x >> 1) & 15;
    int half = blockIdx.x & 1;
    int t    = threadIdx.x;
    __shared__ float2 tw[256];
    if (t < 256) { float s, c; sincosf(TWO_PI * (float)t * (1.0f/256.0f), &s, &c);
                   tw[t] = make_float2(c, s); }
    __syncthreads();
    int ofs = half*2048 + t*4;       // float offset into 4096-float row
    int h0  = hg*8;
    float Are[8][2], Aim[8][2], Bre[8][2], Bim[8][2];
#pragma unroll
    for (int hh = 0; hh < 8; ++hh) {
        Are[hh][0]=Are[hh][1]=Aim[hh][0]=Aim[hh][1]=0.f;
        Bre[hh][0]=Bre[hh][1]=Bim[hh][0]=Bim[hh][1]=0.f;
    }
    const float* obase = WS + OFF_OF + (size_t)b*64*4096 + ofs;
    float4 of0  = *(const float4*)(obase);                 // kxidx 0  (kx=0)
    float4 of32 = *(const float4*)(obase + (size_t)32*4096); // kxidx 32 (kx=224)
    float A128r0 = of0.x + of32.x, A128i0 = of0.y + of32.y;
    float A128r1 = of0.z + of32.z, A128i1 = of0.w + of32.w;
#pragma unroll
    for (int hh = 0; hh < 8; ++hh) {
        int h = h0 + hh;
        Are[hh][0] += of0.x; Aim[hh][0] += of0.y;
        Are[hh][1] += of0.z; Aim[hh][1] += of0.w;
        float2 cs = tw[(224*h) & 255];
        Are[hh][0]=fmaf(of32.x,cs.x,Are[hh][0]); Aim[hh][0]=fmaf(of32.y,cs.x,Aim[hh][0]);
        Are[hh][1]=fmaf(of32.z,cs.x,Are[hh][1]); Aim[hh][1]=fmaf(of32.w,cs.x,Aim[hh][1]);
        Bre[hh][0]=fmaf(of32.x,cs.y,Bre[hh][0]); Bim[hh][0]=fmaf(of32.y,cs.y,Bim[hh][0]);
        Bre[hh][1]=fmaf(of32.z,cs.y,Bre[hh][1]); Bim[hh][1]=fmaf(of32.w,cs.y,Bim[hh][1]);
    }
    for (int mm = 1; mm < 32; ++mm) {
        float4 oa = *(const float4*)(obase + (size_t)mm*4096);
        float4 ob = *(const float4*)(obase + (size_t)(64-mm)*4096);
        float Pr0 = oa.x + ob.x, Pi0 = oa.y + ob.y;
        float Pr1 = oa.z + ob.z, Pi1 = oa.w + ob.w;
        float Mr0 = oa.x - ob.x, Mi0 = oa.y - ob.y;
        float Mr1 = oa.z - ob.z, Mi1 = oa.w - ob.w;
#pragma unroll
        for (int hh = 0; hh < 8; ++hh) {
            float2 cs = tw[(mm*(h0+hh)) & 255];
            float C = cs.x, S = cs.y;
            Are[hh][0]=fmaf(Pr0,C,Are[hh][0]); Aim[hh][0]=fmaf(Pi0,C,Aim[hh][0]);
            Are[hh][1]=fmaf(Pr1,C,Are[hh][1]); Aim[hh][1]=fmaf(Pi1,C,Aim[hh][1]);
            Bre[hh][0]=fmaf(Mr0,S,Bre[hh][0]); Bim[hh][0]=fmaf(Mi0,S,Bim[hh][0]);
            Bre[hh][1]=fmaf(Mr1,S,Bre[hh][1]); Bim[hh][1]=fmaf(Mi1,S,Bim[hh][1]);
        }
        if (hg == 0) {               // h=128: c = (-1)^m, s = 0
            float sg = (mm & 1) ? -1.f : 1.f;
            A128r0 = fmaf(sg, Pr0, A128r0); A128i0 = fmaf(sg, Pi0, A128i0);
            A128r1 = fmaf(sg, Pr1, A128r1); A128i1 = fmaf(sg, Pi1, A128i1);
        }
    }
#pragma unroll
    for (int hh = 0; hh < 8; ++hh) {
        int h = h0 + hh;
        float* dp = WS + (size_t)(b*256 + h)*4096 + ofs;
        *(float4*)dp = make_float4(Are[hh][0]-Bim[hh][0], Aim[hh][0]+Bre[hh][0],
                                   Are[hh][1]-Bim[hh][1], Aim[hh][1]+Bre[hh][1]);
        if (h > 0) {
            float* dq = WS + (size_t)(b*256 + 256 - h)*4096 + ofs;
            *(float4*)dq = make_float4(Are[hh][0]+Bim[hh][0], Aim[hh][0]-Bre[hh][0],
                                       Are[hh][1]+Bim[hh][1], Aim[hh][1]-Bre[hh][1]);
        }
    }
    if (hg == 0) {
        float* dp = WS + (size_t)(b*256 + 128)*4096 + ofs;
        *(float4*)dp = make_float4(A128r0, A128i0, A128r1, A128i1);
    }
}

// ---------------- K5: inverse rfft over w + bias, no shuffles ----------------
// block per (b,h), 256 thr: stage tmp row (16 KB) in LDS; lane = channel,
// full 32-ky loop in registers; wave w owns j = w*16+1 .. w*16+16 (wave 3:
// 15 j's + the four edge columns).
__global__ __launch_bounds__(256) void k5_idft_w(const float* __restrict__ bias,
                                                 const float* __restrict__ WS,
                                                 float* __restrict__ out) {
    int bh = blockIdx.x;             // 0..4095
    int t  = threadIdx.x;
    __shared__ float2 tw[256];
    __shared__ float  lt[4096];
    { float s, c; sincosf(TWO_PI * (float)t * (1.0f/256.0f), &s, &c);
      tw[t] = make_float2(c, s); }
    const float4* T4 = (const float4*)(WS + (size_t)bh*4096);
#pragma unroll
    for (int q = 0; q < 4; ++q)
        ((float4*)lt)[t + 256*q] = T4[t + 256*q];
    __syncthreads();
    int w = t >> 6, o = t & 63;
    float trr[32], tii[32];
    const float2* l2 = (const float2*)lt;
#pragma unroll
    for (int ky = 0; ky < 32; ++ky) {
        float2 p = l2[ky*64 + o];
        float sc = (ky == 0) ? 1.f : 2.f;   // Hermitian doubling; bin0 real-only
        trr[ky] = p.x*sc; tii[ky] = p.y*sc;
    }
    float bv = bias[o];
    float* R = out + (size_t)bh*16384 + o;
    int j0 = w*16;
    for (int jj = 1; jj <= 16; ++jj) {
        int j = j0 + jj;
        if (j < 64) {
            float E0=0.f, Od0=0.f, E1=0.f, Od1=0.f;
#pragma unroll
            for (int ky = 0; ky < 32; ++ky) {
                float2 cs = tw[(ky*j) & 255];
                float C = cs.x, S = cs.y;
                E0  = fmaf(trr[ky], C, E0);
                Od0 = fmaf(tii[ky], S, Od0);
                if ((ky & 3) == 0)      { E1 = fmaf(trr[ky], C, E1);
                                          Od1 = fmaf(tii[ky], S, Od1); }
                else if ((ky & 3) == 1) { E1 = fmaf(-trr[ky], S, E1);
                                          Od1 = fmaf(tii[ky], C, Od1); }
                else if ((ky & 3) == 2) { E1 = fmaf(-trr[ky], C, E1);
                                          Od1 = fmaf(-tii[ky], S, Od1); }
                else                    { E1 = fmaf(trr[ky], S, E1);
                                          Od1 = fmaf(-tii[ky], C, Od1); }
            }
            R[j*64]       = bv + E0 - Od0;
            R[(256-j)*64] = bv + E0 + Od0;
            R[(64+j)*64]  = bv + E1 - Od1;
            R[(192-j)*64] = bv + E1 + Od1;
        } else {                     // wave 3, jj==16: edge columns 0,64,128,192
            float sA=0.f, sB=0.f, P1=0.f, P2=0.f;
#pragma unroll
            for (int ky = 0; ky < 32; ++ky) {
                sA += trr[ky];
                sB += (ky & 1) ? -trr[ky] : trr[ky];
                if ((ky & 3) == 0) P1 += trr[ky];
                else if ((ky & 3) == 2) P1 -= trr[ky];
                else if ((ky & 3) == 1) P2 += tii[ky];
                else P2 -= tii[ky];
            }
            R[0]      = bv + sA;
            R[64*64]  = bv + P1 - P2;
            R[128*64] = bv + sB;
            R[192*64] = bv + P1 + P2;
        }
    }
}

extern "C" void kernel_launch(void* const* d_in, const int* in_sizes, int n_in,
                              void* d_out, int out_size, void* d_ws, size_t ws_size,
                              hipStream_t stream) {
    (void)in_sizes; (void)n_in; (void)out_size;
    if (ws_size < WS_FLOATS_NEEDED * sizeof(float)) return;  // ws observed = 1 GiB
    const float* x    = (const float*)d_in[0];
    const float* w1re = (const float*)d_in[1];
    const float* w1im = (const float*)d_in[2];
    const float* w2re = (const float*)d_in[3];
    const float* w2im = (const float*)d_in[4];
    const float* bias = (const float*)d_in[5];
    float* O  = (float*)d_out;
    float* WS = (float*)d_ws;

    k1_dft_w <<<1024, 256, 0, stream>>>(x, WS);
    k2_dft_h <<< 512, 512, 0, stream>>>(WS);
    k3_mix   <<< 256, 512, 0, stream>>>(w1re, w1im, w2re, w2im, WS);
    k4_idft_h<<< 512, 512, 0, stream>>>(WS);
    k5_idft_w<<<4096, 256, 0, stream>>>(bias, WS, O);
}

// Round 9
// 271.413 us; speedup vs baseline: 1.6295x; 1.1416x over previous
//
#include <hip/hip_runtime.h>
#include <math.h>

#define NB 16
#define NH 256
#define NW 256
#define TWO_PI 6.28318530717958647692f
#define FSCALE (1.0f/65536.0f)       // norm='forward' 1/(H*W)

// Workspace layout (floats). ws_size = 1 GiB; we use 84 MB.
//   [0, 2^24)            G1[b][h][comp][ky][i] planes (K1 -> K2): re at
//                        bh*4096 + ky*64 + i, im at +2048. Then reused as
//                        tmp[b][h][ky][o] interleaved cplx (K4 -> K5).
//   [2^24, 2^24+2^22)    X_ft[b][kx][ky][i]  (K2 -> K3)
//   [2^24+2^22, +2^23)   out_ft[b][kx][ky][o] (K3 -> K4)
#define OFF_X  ((size_t)1 << 24)
#define OFF_OF (((size_t)1 << 24) + ((size_t)1 << 22))
#define WS_FLOATS_NEEDED (((size_t)1 << 24) + ((size_t)2 << 22))

typedef __attribute__((ext_vector_type(8))) short short8;
typedef __attribute__((ext_vector_type(4))) float f32x4;

__device__ __forceinline__ unsigned short f2bf(float f) {
    unsigned int u = __float_as_uint(f);
    unsigned int r = (u + 0x7FFFu + ((u >> 16) & 1u)) >> 16;
    return (unsigned short)r;
}

// ---------------- K1: forward DFT over w via bf16 MFMA ----------------------
#define XPITCH 264   // ushorts per LDS row (256 + 8 pad -> <=2-way conflicts)
__global__ __launch_bounds__(256) void k1_dft_w(const float* __restrict__ x,
                                                float* __restrict__ WS) {
    __shared__ unsigned short Al[64 * XPITCH];   // T[m][w] bf16, 33 KB
    __shared__ unsigned short Xl[64 * XPITCH];   // x^T[i][w] bf16, 33 KB
    int t = threadIdx.x;
    {   // build T: thread t covers m = t>>2, w = (t&3)*64 .. +63
        int m  = t >> 2;
        int w0 = (t & 3) * 64;
        int ky = m & 31;
        for (int dw = 0; dw < 64; ++dw) {
            int w = w0 + dw;
            float ang = TWO_PI * (float)((ky * w) & 255) * (1.0f/256.0f);
            float s, c; sincosf(ang, &s, &c);
            float v = (m < 32) ? c : -s;
            Al[m * XPITCH + w] = f2bf(v * FSCALE);
        }
    }
    int wave = t >> 6, lane = t & 63;
    int col = lane & 15, kq = lane >> 4;
    for (int u = 0; u < 4; ++u) {
        int bh = blockIdx.x * 4 + u;
        __syncthreads();             // T ready / previous compute done
        {   // stage x^T: thread t owns w-row t; stride-2B LDS writes
            const float* xs = x + (size_t)bh * 16384 + t * 64;
            for (int i4 = 0; i4 < 16; ++i4) {
                float4 v = *(const float4*)(xs + i4*4);
                Xl[(i4*4+0)*XPITCH + t] = f2bf(v.x);
                Xl[(i4*4+1)*XPITCH + t] = f2bf(v.y);
                Xl[(i4*4+2)*XPITCH + t] = f2bf(v.z);
                Xl[(i4*4+3)*XPITCH + t] = f2bf(v.w);
            }
        }
        __syncthreads();
        f32x4 acc[4];
#pragma unroll
        for (int n = 0; n < 4; ++n) acc[n] = (f32x4){0.f, 0.f, 0.f, 0.f};
#pragma unroll
        for (int kk = 0; kk < 8; ++kk) {
            int k = kk*32 + kq*8;
            short8 af = *(const short8*)&Al[(wave*16 + col) * XPITCH + k];
#pragma unroll
            for (int n = 0; n < 4; ++n) {
                short8 bf = *(const short8*)&Xl[(n*16 + col) * XPITCH + k];
                acc[n] = __builtin_amdgcn_mfma_f32_16x16x32_bf16(af, bf, acc[n], 0, 0, 0);
            }
        }
        int comp = wave >> 1;        // 0 = re, 1 = im
        int kyb  = (wave & 1) * 16;
        float* gp = WS + (size_t)bh * 4096 + comp * 2048;
#pragma unroll
        for (int n = 0; n < 4; ++n)
#pragma unroll
            for (int q = 0; q < 4; ++q) {
                int ky = kyb + kq*4 + q;
                gp[ky*64 + n*16 + col] = acc[n][q];
            }
    }
}

// ---------------- K2: forward DFT over h, LDS-staged, +/- symmetry ----------
__global__ __launch_bounds__(512) void k2_dft_h(float* __restrict__ WS) {
    int b  = blockIdx.x >> 5;
    int ky = blockIdx.x & 31;
    int t  = threadIdx.x;
    int i  = t & 63;
    int kg = t >> 6;                 // 0..7
    __shared__ float2 tw[256];
    __shared__ float  lgf[129*128];  // 66 KB; slot = [re 64 | im 64]
    if (t < 256) { float s, c; sincosf(TWO_PI * (float)t * (1.0f/256.0f), &s, &c);
                   tw[t] = make_float2(c, s); }
    const float* gb = WS + (size_t)b*256*4096 + ky*64;    // + h*4096 (+comp*2048)

    for (int n = t; n < 127*32; n += 512) {
        int slot = n >> 5, q = n & 31;
        int comp = q >> 4, qq = q & 15;
        int row  = (slot < 64) ? slot : slot + 129;
        ((float4*)lgf)[slot*32 + q] =
            *(const float4*)(gb + (size_t)row*4096 + comp*2048 + qq*4);
    }
    __syncthreads();

    float Ar[4]={0,0,0,0}, Ai[4]={0,0,0,0};
    float Br[4]={0,0,0,0}, Bi[4]={0,0,0,0};
    float S0r = 0.f, S0i = 0.f;      // kx=0 accumulator (kg==0 slot 0 only)

    for (int j = 1; j < 64; ++j) {
        float g0r = lgf[j*128 + i],        g0i = lgf[j*128 + 64 + i];
        float g1r = lgf[(127-j)*128 + i],  g1i = lgf[(127-j)*128 + 64 + i];
        float P0r = g0r + g1r, P0i = g0i + g1i;
        float M0r = g0r - g1r, M0i = g0i - g1i;
#pragma unroll
        for (int q = 0; q < 4; ++q) {
            int m = kg*4 + q;
            if (kg == 0 && q == 0) {
                S0r += P0r; S0i += P0i;
                float2 cs = tw[(224*j) & 255];
                Ar[0]=fmaf(P0r,cs.x,Ar[0]); Ai[0]=fmaf(P0i,cs.x,Ai[0]);
                Br[0]=fmaf(M0r,cs.y,Br[0]); Bi[0]=fmaf(M0i,cs.y,Bi[0]);
            } else {
                float2 cs = tw[(m*j) & 255];
                Ar[q]=fmaf(P0r,cs.x,Ar[q]); Ai[q]=fmaf(P0i,cs.x,Ai[q]);
                Br[q]=fmaf(M0r,cs.y,Br[q]); Bi[q]=fmaf(M0i,cs.y,Bi[q]);
            }
        }
    }
    {   // edge row 0 (slot 0)
        float e0r = lgf[i], e0i = lgf[64 + i];
#pragma unroll
        for (int q = 0; q < 4; ++q) {
            if (kg == 0 && q == 0) { S0r += e0r; S0i += e0i; }
            Ar[q] += e0r; Ai[q] += e0i;
        }
    }
    __syncthreads();
    for (int n = t; n < 129*32; n += 512) {
        int slot = n >> 5, q = n & 31;
        int comp = q >> 4, qq = q & 15;
        ((float4*)lgf)[slot*32 + q] =
            *(const float4*)(gb + (size_t)(slot+64)*4096 + comp*2048 + qq*4);
    }
    __syncthreads();

    for (int j = 1; j < 64; ++j) {
        float g2r = lgf[j*128 + i],        g2i = lgf[j*128 + 64 + i];
        float g3r = lgf[(128-j)*128 + i],  g3i = lgf[(128-j)*128 + 64 + i];
        float P1r = g2r + g3r, P1i = g2i + g3i;
        float M1r = g2r - g3r, M1i = g2i - g3i;
#pragma unroll
        for (int q = 0; q < 4; ++q) {
            int m = kg*4 + q;
            if (kg == 0 && q == 0) {
                S0r += P1r; S0i += P1i;
                float2 cs = tw[(224*j) & 255];   // 224*64 % 256 == 0: identity rot
                Ar[0]=fmaf(P1r,cs.x,Ar[0]); Ai[0]=fmaf(P1i,cs.x,Ai[0]);
                Br[0]=fmaf(M1r,cs.y,Br[0]); Bi[0]=fmaf(M1i,cs.y,Bi[0]);
            } else {
                float2 cs = tw[(m*j) & 255];
                float C = cs.x, S = cs.y, C2, S2;
                if (q == 0)      { C2 = C;  S2 = S;  }
                else if (q == 1) { C2 = -S; S2 = C;  }
                else if (q == 2) { C2 = -C; S2 = -S; }
                else             { C2 = S;  S2 = -C; }
                Ar[q]=fmaf(P1r,C2,Ar[q]); Ai[q]=fmaf(P1i,C2,Ai[q]);
                Br[q]=fmaf(M1r,S2,Br[q]); Bi[q]=fmaf(M1i,S2,Bi[q]);
            }
        }
    }
    {   // edges rows 64 (slot 0), 128 (slot 64), 192 (slot 128)
        float e64r  = lgf[i],          e64i  = lgf[64 + i];
        float e128r = lgf[64*128 + i], e128i = lgf[64*128 + 64 + i];
        float e192r = lgf[128*128 + i],e192i = lgf[128*128 + 64 + i];
        float p64r = e64r + e192r, p64i = e64i + e192i;
        float m64r = e64r - e192r, m64i = e64i - e192i;
#pragma unroll
        for (int q = 0; q < 4; ++q) {
            if (kg == 0 && q == 0) {
                S0r += e64r + e128r + e192r;
                S0i += e64i + e128i + e192i;
                Ar[0] += e128r + p64r;
                Ai[0] += e128i + p64i;
            } else {
                if ((q & 1) == 0) { Ar[q] += e128r; Ai[q] += e128i; }
                else              { Ar[q] -= e128r; Ai[q] -= e128i; }
                if (q == 0)      { Ar[q] += p64r; Ai[q] += p64i; }
                else if (q == 1) { Br[q] += m64r; Bi[q] += m64i; }
                else if (q == 2) { Ar[q] -= p64r; Ai[q] -= p64i; }
                else             { Br[q] -= m64r; Bi[q] -= m64i; }
            }
        }
    }
#pragma unroll
    for (int q = 0; q < 4; ++q) {
        int m = kg*4 + q;
        if (kg == 0 && q == 0) {
            float* p0w = WS + OFF_X + (((size_t)b*64 + 0)*32 + ky)*128 + 2*i;
            *(float2*)p0w = make_float2(S0r, S0i);
            float* p32 = WS + OFF_X + (((size_t)b*64 + 32)*32 + ky)*128 + 2*i;
            *(float2*)p32 = make_float2(Ar[0] + Bi[0], Ai[0] - Br[0]);
        } else {
            float* pa = WS + OFF_X + (((size_t)b*64 + m)*32 + ky)*128 + 2*i;
            *(float2*)pa = make_float2(Ar[q] + Bi[q], Ai[q] - Br[q]);
            float* pb = WS + OFF_X + (((size_t)b*64 + (64-m))*32 + ky)*128 + 2*i;
            *(float2*)pb = make_float2(Ar[q] - Bi[q], Ai[q] + Br[q]);
        }
    }
}

// ---------------- K3: channel mixing (complex 64x64 per (kx,ky)) -------------
__global__ __launch_bounds__(512) void k3_mix(const float* __restrict__ w1re,
                                              const float* __restrict__ w1im,
                                              const float* __restrict__ w2re,
                                              const float* __restrict__ w2im,
                                              float* __restrict__ WS) {
    int kx  = blockIdx.x & 63;       // 0..63
    int kyq = blockIdx.x >> 6;       // 0..3; ky = kyq*8 + kyl
    int t   = threadIdx.x;
    __shared__ float2 lx[8192];      // [b][ky8][i] = 64 KB
    __shared__ float  lw[2][2][4][576];  // [buf][re/im][i4][o*9+ky8] = 36 KB
    const float* wre = (kx < 32) ? w1re : w2re;
    const float* wim = (kx < 32) ? w1im : w2im;
    int m = kx & 31;
    for (int n = t; n < 8192; n += 512) {
        int bb = n >> 9, ky8 = (n >> 6) & 7, ii = n & 63;
        lx[n] = *(const float2*)(WS + OFF_X
                 + (((size_t)bb*64 + kx)*32 + kyq*8 + ky8)*128 + 2*ii);
    }
    int sarr = t & 1, so = (t >> 1) & 63, si4 = t >> 7;
    const float* wsrc = sarr ? wim : wre;
    size_t sbase = (size_t)m*32 + kyq*8;
    int kyl = t >> 6;                // 0..7
    int o   = t & 63;
    int kyg = kyq*8 + kyl;
    float ar[16], ai[16];
#pragma unroll
    for (int bb = 0; bb < 16; ++bb) { ar[bb] = 0.f; ai[bb] = 0.f; }

    float4 wa, wb;
    {
        const float* src = wsrc + ((size_t)(si4*64 + so)*1024 + sbase);
        wa = *(const float4*)src; wb = *(const float4*)(src + 4);
        float* dst = &lw[0][sarr][si4][so*9];
        dst[0]=wa.x; dst[1]=wa.y; dst[2]=wa.z; dst[3]=wa.w;
        dst[4]=wb.x; dst[5]=wb.y; dst[6]=wb.z; dst[7]=wb.w;
    }
    __syncthreads();

    for (int k = 0; k < 16; ++k) {
        int i0 = k*4;
        float4 na, nb;
        if (k < 15) {
            const float* src = wsrc + ((size_t)((i0+4+si4)*64 + so)*1024 + sbase);
            na = *(const float4*)src; nb = *(const float4*)(src + 4);
        }
#pragma unroll
        for (int di = 0; di < 4; ++di) {
            float wr = lw[k & 1][0][di][o*9 + kyl];
            float wi = lw[k & 1][1][di][o*9 + kyl];
            int ii = i0 + di;
#pragma unroll
            for (int bb = 0; bb < 16; ++bb) {
                float2 xv = lx[(bb*8 + kyl)*64 + ii];
                ar[bb] = fmaf(xv.x, wr, fmaf(-xv.y, wi, ar[bb]));
                ai[bb] = fmaf(xv.x, wi, fmaf( xv.y, wr, ai[bb]));
            }
        }
        if (k < 15) {
            float* dst = &lw[(k+1) & 1][sarr][si4][so*9];
            dst[0]=na.x; dst[1]=na.y; dst[2]=na.z; dst[3]=na.w;
            dst[4]=nb.x; dst[5]=nb.y; dst[6]=nb.z; dst[7]=nb.w;
        }
        __syncthreads();
    }
#pragma unroll
    for (int bb = 0; bb < 16; ++bb) {
        float* cp = WS + OFF_OF + (((size_t)bb*64 + kx)*32 + kyg)*128 + 2*o;
        *(float2*)cp = make_float2(ar[bb], ai[bb]);
    }
}

// ---------------- K4: inverse DFT over h, re-blocked per (b,ky) --------------
// Each block stages ONLY its own 32 KB of-slice (kills the 32x L3 re-read).
// Thread (o = t&63, hg = t>>6): 16 h-leads hg*16+ld, writes lead+mirror;
// hg==0 also writes h=128. fp32 throughout.
__global__ __launch_bounds__(512) void k4_idft_h(float* __restrict__ WS) {
    int b  = blockIdx.x >> 5;        // 0..15
    int ky = blockIdx.x & 31;
    int t  = threadIdx.x;
    __shared__ float2 tw[256];
    __shared__ float2 ofl[4096];     // [kx][o] complex, 32 KB
    if (t < 256) { float s, c; sincosf(TWO_PI * (float)t * (1.0f/256.0f), &s, &c);
                   tw[t] = make_float2(c, s); }
    for (int n = t; n < 4096; n += 512) {
        int kx = n >> 6, oo = n & 63;
        ofl[n] = *(const float2*)(WS + OFF_OF
                  + (((size_t)b*64 + kx)*32 + ky)*128 + 2*oo);
    }
    __syncthreads();
    int o = t & 63, hg = t >> 6;     // hg = wave index, 0..7
    float Ar[16], Ai[16], Br[16], Bi[16];
    float2 of0  = ofl[0*64 + o];     // kx=0
    float2 of32 = ofl[32*64 + o];    // kx=224
    float A128r = of0.x + of32.x, A128i = of0.y + of32.y;
#pragma unroll
    for (int ld = 0; ld < 16; ++ld) {
        int h = hg*16 + ld;
        float2 cs = tw[(224*h) & 255];
        Ar[ld] = fmaf(of32.x, cs.x, of0.x);
        Ai[ld] = fmaf(of32.y, cs.x, of0.y);
        Br[ld] = of32.x * cs.y;
        Bi[ld] = of32.y * cs.y;
    }
    for (int mm = 1; mm < 32; ++mm) {
        float2 oa = ofl[mm*64 + o];
        float2 ob = ofl[(64-mm)*64 + o];
        float Pr = oa.x + ob.x, Pi = oa.y + ob.y;
        float Mr = oa.x - ob.x, Mi = oa.y - ob.y;
#pragma unroll
        for (int ld = 0; ld < 16; ++ld) {
            float2 cs = tw[(mm*(hg*16 + ld)) & 255];
            Ar[ld] = fmaf(Pr, cs.x, Ar[ld]); Ai[ld] = fmaf(Pi, cs.x, Ai[ld]);
            Br[ld] = fmaf(Mr, cs.y, Br[ld]); Bi[ld] = fmaf(Mi, cs.y, Bi[ld]);
        }
        if (hg == 0) {               // h=128: c = (-1)^m, s = 0
            float sg = (mm & 1) ? -1.f : 1.f;
            A128r = fmaf(sg, Pr, A128r); A128i = fmaf(sg, Pi, A128i);
        }
    }
#pragma unroll
    for (int ld = 0; ld < 16; ++ld) {
        int h = hg*16 + ld;
        float* dp = WS + (size_t)(b*256 + h)*4096 + (ky*64 + o)*2;
        *(float2*)dp = make_float2(Ar[ld] - Bi[ld], Ai[ld] + Br[ld]);
        if (h > 0) {
            float* dq = WS + (size_t)(b*256 + 256 - h)*4096 + (ky*64 + o)*2;
            *(float2*)dq = make_float2(Ar[ld] + Bi[ld], Ai[ld] - Br[ld]);
        }
    }
    if (hg == 0) {
        float* dp = WS + (size_t)(b*256 + 128)*4096 + (ky*64 + o)*2;
        *(float2*)dp = make_float2(A128r, A128i);
    }
}

// ---------------- K5: inverse rfft over w via bf16 MFMA + bias ---------------
// Per (b,h): out[256 w, 64 o] = T5[256 w, 64 k] tmp2[64 k, 64 o]; k<32: re
// with T5 = sc*cos; k>=32: im with T5 = -sc*sin (sc = Hermitian 2, bin0 sc=1;
// bin0 imag col vanishes since sin(0)=0). Block = 4 waves, 4 (b,h); T5 built
// once. Fragment pattern identical to k1 (verified).
#define APITCH 72
__global__ __launch_bounds__(256) void k5_idft_w(const float* __restrict__ bias,
                                                 const float* __restrict__ WS,
                                                 float* __restrict__ out) {
    int t = threadIdx.x;
    __shared__ float2 tw[256];
    __shared__ unsigned short T5[256 * APITCH];  // [w][k] bf16, 36 KB
    __shared__ unsigned short Bl[64 * APITCH];   // [o][k] bf16, 9 KB
    { float s, c; sincosf(TWO_PI * (float)t * (1.0f/256.0f), &s, &c);
      tw[t] = make_float2(c, s); }
    __syncthreads();
    {   // build T5 row w = t
        int w = t;
#pragma unroll
        for (int ky = 0; ky < 32; ++ky) {
            float2 cs = tw[(ky * w) & 255];
            float sc = ky ? 2.f : 1.f;
            T5[w*APITCH + ky]      = f2bf(sc * cs.x);
            T5[w*APITCH + 32 + ky] = f2bf(-sc * cs.y);
        }
    }
    int o = t & 63, kg = t >> 6;     // staging roles
    int wave = t >> 6, col = t & 15, kq = (t >> 4) & 3;
    float bv[4];
#pragma unroll
    for (int n = 0; n < 4; ++n) bv[n] = bias[n*16 + col];

    for (int u = 0; u < 4; ++u) {
        int bh = blockIdx.x * 4 + u;
        __syncthreads();             // prior MFMA reads done (u=0: T5 ready)
        {   // stage Bl[o][k] from tmp row (fp32 interleaved cplx)
            const float* tp = WS + (size_t)bh * 4096;
#pragma unroll
            for (int kk = 0; kk < 8; ++kk) {
                int ky = kg*8 + kk;
                float2 v = *(const float2*)(tp + (ky*64 + o)*2);
                Bl[o*APITCH + ky]      = f2bf(v.x);
                Bl[o*APITCH + 32 + ky] = f2bf(v.y);
            }
        }
        __syncthreads();
        f32x4 acc[4][4];             // [m-tile][n-tile]
#pragma unroll
        for (int mt = 0; mt < 4; ++mt)
#pragma unroll
            for (int n = 0; n < 4; ++n) acc[mt][n] = (f32x4){0.f,0.f,0.f,0.f};
#pragma unroll
        for (int kk = 0; kk < 2; ++kk) {
            short8 af[4];
#pragma unroll
            for (int mt = 0; mt < 4; ++mt)
                af[mt] = *(const short8*)&T5[(wave*64 + mt*16 + col)*APITCH
                                             + kk*32 + kq*8];
#pragma unroll
            for (int n = 0; n < 4; ++n) {
                short8 bf = *(const short8*)&Bl[(n*16 + col)*APITCH
                                                + kk*32 + kq*8];
#pragma unroll
                for (int mt = 0; mt < 4; ++mt)
                    acc[mt][n] = __builtin_amdgcn_mfma_f32_16x16x32_bf16(
                                     af[mt], bf, acc[mt][n], 0, 0, 0);
            }
        }
        float* R = out + (size_t)bh * 16384;
#pragma unroll
        for (int mt = 0; mt < 4; ++mt)
#pragma unroll
            for (int n = 0; n < 4; ++n)
#pragma unroll
                for (int q = 0; q < 4; ++q) {
                    int w = wave*64 + mt*16 + kq*4 + q;
                    R[w*64 + n*16 + col] = acc[mt][n][q] + bv[n];
                }
    }
}

extern "C" void kernel_launch(void* const* d_in, const int* in_sizes, int n_in,
                              void* d_out, int out_size, void* d_ws, size_t ws_size,
                              hipStream_t stream) {
    (void)in_sizes; (void)n_in; (void)out_size;
    if (ws_size < WS_FLOATS_NEEDED * sizeof(float)) return;  // ws observed = 1 GiB
    const float* x    = (const float*)d_in[0];
    const float* w1re = (const float*)d_in[1];
    const float* w1im = (const float*)d_in[2];
    const float* w2re = (const float*)d_in[3];
    const float* w2im = (const float*)d_in[4];
    const float* bias = (const float*)d_in[5];
    float* O  = (float*)d_out;
    float* WS = (float*)d_ws;

    k1_dft_w <<<1024, 256, 0, stream>>>(x, WS);
    k2_dft_h <<< 512, 512, 0, stream>>>(WS);
    k3_mix   <<< 256, 512, 0, stream>>>(w1re, w1im, w2re, w2im, WS);
    k4_idft_h<<< 512, 512, 0, stream>>>(WS);
    k5_idft_w<<<1024, 256, 0, stream>>>(bias, WS, O);
}